// Round 4
// baseline (376.672 us; speedup 1.0000x reference)
//
#include <hip/hip_runtime.h>

typedef __attribute__((ext_vector_type(8))) short short8;
typedef __attribute__((ext_vector_type(4))) float floatx4;
typedef __attribute__((ext_vector_type(4))) unsigned int uintx4;
typedef __attribute__((ext_vector_type(4))) unsigned short ushortx4;

#define D_NODE 64
#define D_OUT  64
#define ITERS 4

static __device__ __forceinline__ unsigned short f2bf(float x) {
    unsigned int u = __float_as_uint(x);
    unsigned int r = u + 0x7FFFu + ((u >> 16) & 1u);
    return (unsigned short)(r >> 16);
}

static __device__ __forceinline__ short8 cvt2(floatx4 x, floatx4 y) {
    short8 a;
    a[0] = (short)f2bf(x[0]); a[1] = (short)f2bf(x[1]);
    a[2] = (short)f2bf(x[2]); a[3] = (short)f2bf(x[3]);
    a[4] = (short)f2bf(y[0]); a[5] = (short)f2bf(y[1]);
    a[6] = (short)f2bf(y[2]); a[7] = (short)f2bf(y[3]);
    return a;
}

static __device__ __forceinline__ short8 load_cvt(const float* __restrict__ p) {
    return cvt2(*(const floatx4*)p, *(const floatx4*)(p + 4));
}

static __device__ __forceinline__ floatx4 ntload4(const float* __restrict__ p) {
    return __builtin_nontemporal_load((const floatx4*)p);
}

// Permuted W packing. A-fragment (lane l, elem j) = W[k][col] with
//   k = kbase + (l>>4)*8 + j,  col = 4*(l&15) + ct
// so the MFMA D-value acc[ct][reg j] (D-row r = (l>>4)*4+j) is out-col
//   4*r + ct = 16*(l>>4) + 4*j + ct  -> lane owns 16 CONTIGUOUS out cols.
// Memory layouts of out / NC stay canonical; permutation is only in packing.
// wpe: 8 frags (fi = kstep*4 + ct) of W[0:64].
// wpn: 16 frags (fi = kstep*8 + ct); ct<4 -> W[64:128] (recv), ct>=4 -> W[128:192] (send).
// gc : b + globals @ W[192:224]  (canonical col order)
__global__ void pack2_kernel(const float* __restrict__ W, const float* __restrict__ b,
                             const float* __restrict__ g,
                             unsigned short* __restrict__ wpe,
                             unsigned short* __restrict__ wpn,
                             float* __restrict__ gc) {
    int tid = blockIdx.x * 256 + threadIdx.x;
    if (tid < 512) {
        int lane = tid & 63;
        int ct = (tid >> 6) & 3;
        int kstep = tid >> 8;
        int kbase = kstep * 32 + (lane >> 4) * 8;
        int col = 4 * (lane & 15) + ct;
        short8 sv;
#pragma unroll
        for (int j = 0; j < 8; ++j)
            sv[j] = (short)f2bf(W[(size_t)(kbase + j) * D_OUT + col]);
        *(short8*)(wpe + (size_t)tid * 8) = sv;
    } else if (tid < 512 + 1024) {
        int t = tid - 512;
        int lane = t & 63;
        int ct = (t >> 6) & 7;
        int kstep = t >> 9;
        int kk = kstep * 32 + (lane >> 4) * 8;
        int seg = (ct < 4) ? 64 : 128;
        int col = 4 * (lane & 15) + (ct & 3);
        short8 sv;
#pragma unroll
        for (int j = 0; j < 8; ++j)
            sv[j] = (short)f2bf(W[(size_t)(seg + kk + j) * D_OUT + col]);
        *(short8*)(wpn + (size_t)t * 8) = sv;
    } else if (tid < 512 + 1024 + 64) {
        int col = tid - 1536;
        float acc = b[col];
#pragma unroll
        for (int k = 0; k < 32; ++k)
            acc += g[k] * W[(size_t)(192 + k) * D_OUT + col];
        gc[col] = acc;
    }
}

// NC (bf16, canonical cols): NC[i][0:64] = nodes[i]@W[64:128], NC[i][64:128] = nodes[i]@W[128:192]
__global__ __launch_bounds__(256) void node3_kernel(
    const float* __restrict__ nodes, const unsigned short* __restrict__ wpn,
    unsigned short* __restrict__ NCb, int Nn) {
    const int lane = threadIdx.x & 63;
    const int wave = threadIdx.x >> 6;
    const int g = lane >> 4;
    int nbase = blockIdx.x * 64 + wave * 16;
    if (nbase >= Nn) return;

    int na = nbase + (lane & 15);
    bool valid = na < Nn;
    if (!valid) na = Nn - 1;
    const float* pn = nodes + (size_t)na * D_NODE + g * 8;
    short8 N0 = load_cvt(pn);
    short8 N1 = load_cvt(pn + 32);

    floatx4 acc[8];
#pragma unroll
    for (int ct = 0; ct < 8; ++ct) {
        short8 B0 = *(const short8*)(wpn + ((size_t)ct * 64 + lane) * 8);
        short8 B1 = *(const short8*)(wpn + ((size_t)(8 + ct) * 64 + lane) * 8);
        acc[ct] = (floatx4){0.f, 0.f, 0.f, 0.f};
        acc[ct] = __builtin_amdgcn_mfma_f32_16x16x32_bf16(B0, N0, acc[ct], 0, 0, 0);
        acc[ct] = __builtin_amdgcn_mfma_f32_16x16x32_bf16(B1, N1, acc[ct], 0, 0, 0);
    }
    if (valid) {
        unsigned short* pr = NCb + (size_t)na * 128 + 16 * g;
#pragma unroll
        for (int j = 0; j < 4; ++j) {
            ushortx4 rv, sv;
#pragma unroll
            for (int ct = 0; ct < 4; ++ct) { rv[ct] = f2bf(acc[ct][j]); sv[ct] = f2bf(acc[4 + ct][j]); }
            *(ushortx4*)(pr + 4 * j) = rv;
            *(ushortx4*)(pr + 64 + 4 * j) = sv;
        }
    }
}

__global__ __launch_bounds__(256) void edge4_kernel(
    const float* __restrict__ edges,
    const int* __restrict__ recv, const int* __restrict__ send,
    const unsigned short* __restrict__ wpe, const unsigned short* __restrict__ NCb,
    const float* __restrict__ gc, float* __restrict__ out, int E) {

    const int lane = threadIdx.x & 63;
    const int wave = threadIdx.x >> 6;
    const int g = lane >> 4;
    const int e16 = lane & 15;
    const int koff = g * 8;

    short8 Bf[8];
#pragma unroll
    for (int fi = 0; fi < 8; ++fi)
        Bf[fi] = *(const short8*)(wpe + ((size_t)fi * 64 + lane) * 8);

    // gvj[j] = bias+globals for out-cols 16g+4j+{0..3}
    floatx4 gvj[4];
#pragma unroll
    for (int j = 0; j < 4; ++j)
        gvj[j] = *(const floatx4*)(gc + 16 * g + 4 * j);

    const int base = blockIdx.x * (ITERS * 64) + wave * 16;

    int er[ITERS], ri[ITERS], si[ITERS];
#pragma unroll
    for (int it = 0; it < ITERS; ++it) {
        int r = base + it * 64 + e16;
        er[it] = (r < E) ? r : (E - 1);
        ri[it] = recv[er[it]];
        si[it] = send[er[it]];
    }

#pragma unroll
    for (int it = 0; it < ITERS; ++it) {
        // 1) gathers first (cached — want these in L2/L3)
        const unsigned short* pr = NCb + (size_t)ri[it] * 128 + 16 * g;
        const unsigned short* ps = NCb + (size_t)si[it] * 128 + 64 + 16 * g;
        uintx4 r0 = *(const uintx4*)pr;
        uintx4 r1 = *(const uintx4*)(pr + 8);
        uintx4 s0 = *(const uintx4*)ps;
        uintx4 s1 = *(const uintx4*)(ps + 8);

        // 2) streaming edge loads (nontemporal: don't evict NC from L2)
        const float* pe = edges + (size_t)er[it] * D_NODE + koff;
        floatx4 e0 = ntload4(pe);
        floatx4 e1 = ntload4(pe + 4);
        floatx4 e2 = ntload4(pe + 32);
        floatx4 e3 = ntload4(pe + 36);
        short8 A0 = cvt2(e0, e1);
        short8 A1 = cvt2(e2, e3);

        floatx4 acc[4];
#pragma unroll
        for (int ct = 0; ct < 4; ++ct)
            acc[ct] = (floatx4){gvj[0][ct], gvj[1][ct], gvj[2][ct], gvj[3][ct]};
#pragma unroll
        for (int ct = 0; ct < 4; ++ct) {
            acc[ct] = __builtin_amdgcn_mfma_f32_16x16x32_bf16(Bf[ct], A0, acc[ct], 0, 0, 0);
            acc[ct] = __builtin_amdgcn_mfma_f32_16x16x32_bf16(Bf[4 + ct], A1, acc[ct], 0, 0, 0);
        }

        // 3) unpack bf16 gathers and add (exact f32 adds; bf16<<16 is exact)
#pragma unroll
        for (int d = 0; d < 4; ++d) {
            unsigned int rw0 = r0[d], sw0 = s0[d], rw1 = r1[d], sw1 = s1[d];
            // elems w = 2d, 2d+1 (first 8) and 8+2d, 8+2d+1 ; (ct = w&3, j = w>>2)
            float v0 = __uint_as_float(rw0 << 16) + __uint_as_float(sw0 << 16);
            float v1 = __uint_as_float(rw0 & 0xFFFF0000u) + __uint_as_float(sw0 & 0xFFFF0000u);
            float v2 = __uint_as_float(rw1 << 16) + __uint_as_float(sw1 << 16);
            float v3 = __uint_as_float(rw1 & 0xFFFF0000u) + __uint_as_float(sw1 & 0xFFFF0000u);
            int w0 = 2 * d, w1 = 2 * d + 1, w2 = 8 + 2 * d, w3 = 9 + 2 * d;
            acc[w0 & 3][w0 >> 2] += v0;
            acc[w1 & 3][w1 >> 2] += v1;
            acc[w2 & 3][w2 >> 2] += v2;
            acc[w3 & 3][w3 >> 2] += v3;
        }

        // 4) store: lane owns out-cols [16g, 16g+16) of its edge row (nontemporal)
        int row = base + it * 64 + e16;
        if (row < E) {
            float* po = out + (size_t)row * D_OUT + 16 * g;
#pragma unroll
            for (int j = 0; j < 4; ++j) {
                floatx4 v = (floatx4){acc[0][j], acc[1][j], acc[2][j], acc[3][j]};
                __builtin_nontemporal_store(v, (floatx4*)(po + 4 * j));
            }
        }
    }
}

// ---------------- Fallback path (round-1 kernel) if ws too small ----------------

#define NKSTEP 6
#define NFRAG  (NKSTEP * 4)

__global__ void pack_kernel(const float* __restrict__ W, const float* __restrict__ b,
                            const float* __restrict__ g,
                            unsigned short* __restrict__ wp, float* __restrict__ gc) {
    int tid = blockIdx.x * 256 + threadIdx.x;
    if (tid < NFRAG * 64) {
        int lane = tid & 63;
        int ct = (tid >> 6) & 3;
        int kstep = tid >> 8;
        int kbase = kstep * 32 + (lane >> 4) * 8;
        int col = ct * 16 + (lane & 15);
        short8 sv;
#pragma unroll
        for (int j = 0; j < 8; ++j)
            sv[j] = (short)f2bf(W[(size_t)(kbase + j) * D_OUT + col]);
        *(short8*)(wp + (size_t)tid * 8) = sv;
    } else if (tid < NFRAG * 64 + 64) {
        int col = tid - NFRAG * 64;
        float acc = b[col];
#pragma unroll
        for (int k = 0; k < 32; ++k)
            acc += g[k] * W[(size_t)(192 + k) * D_OUT + col];
        gc[col] = acc;
    }
}

__global__ __launch_bounds__(256) void edge_kernel(
    const float* __restrict__ edges, const float* __restrict__ nodes,
    const int* __restrict__ recv, const int* __restrict__ send,
    const unsigned short* __restrict__ wp, const float* __restrict__ gc,
    float* __restrict__ out, int E) {

    const int lane = threadIdx.x & 63;
    const int wave = threadIdx.x >> 6;

    short8 Bf[NFRAG];
#pragma unroll
    for (int fi = 0; fi < NFRAG; ++fi)
        Bf[fi] = *(const short8*)(wp + ((size_t)fi * 64 + lane) * 8);

    const int colbase = lane & 15;
    float gv[4];
#pragma unroll
    for (int ct = 0; ct < 4; ++ct) gv[ct] = gc[ct * 16 + colbase];

    const int koff = (lane >> 4) * 8;

    for (int it = 0; it < ITERS; ++it) {
        int ebase = (blockIdx.x * ITERS + it) * 64 + wave * 16;
        if (ebase >= E) break;

        int ea = ebase + (lane & 15);
        if (ea >= E) ea = E - 1;
        int ri = recv[ea];
        int si = send[ea];

        const float* pe = edges + (size_t)ea * D_NODE + koff;
        const float* pr = nodes + (size_t)ri * D_NODE + koff;
        const float* ps = nodes + (size_t)si * D_NODE + koff;

        short8 A[NKSTEP];
        A[0] = load_cvt(pe);
        A[1] = load_cvt(pe + 32);
        A[2] = load_cvt(pr);
        A[3] = load_cvt(pr + 32);
        A[4] = load_cvt(ps);
        A[5] = load_cvt(ps + 32);

        floatx4 acc[4];
#pragma unroll
        for (int ct = 0; ct < 4; ++ct)
            acc[ct] = (floatx4){gv[ct], gv[ct], gv[ct], gv[ct]};

#pragma unroll
        for (int ks = 0; ks < NKSTEP; ++ks) {
#pragma unroll
            for (int ct = 0; ct < 4; ++ct)
                acc[ct] = __builtin_amdgcn_mfma_f32_16x16x32_bf16(
                    A[ks], Bf[ks * 4 + ct], acc[ct], 0, 0, 0);
        }

        int crow = ebase + (lane >> 4) * 4;
#pragma unroll
        for (int ct = 0; ct < 4; ++ct) {
#pragma unroll
            for (int r4 = 0; r4 < 4; ++r4) {
                int row = crow + r4;
                if (row < E)
                    out[(size_t)row * D_OUT + ct * 16 + colbase] = acc[ct][r4];
            }
        }
    }
}

extern "C" void kernel_launch(void* const* d_in, const int* in_sizes, int n_in,
                              void* d_out, int out_size, void* d_ws, size_t ws_size,
                              hipStream_t stream) {
    const float* edges = (const float*)d_in[0];
    const float* nodes = (const float*)d_in[1];
    const float* glob  = (const float*)d_in[2];
    const int*   recv  = (const int*)d_in[3];
    const int*   send  = (const int*)d_in[4];
    const float* W     = (const float*)d_in[5];
    const float* b     = (const float*)d_in[6];
    float* out = (float*)d_out;

    int E  = in_sizes[0] / D_NODE;
    int Nn = in_sizes[1] / D_NODE;

    size_t nc_bytes  = (size_t)Nn * 128 * 2;   // bf16 NC
    size_t wpe_bytes = 512 * 8 * 2;
    size_t wpn_bytes = 1024 * 8 * 2;
    size_t need = nc_bytes + wpe_bytes + wpn_bytes + 256;

    int nblk = (E + ITERS * 64 - 1) / (ITERS * 64);

    if (ws_size >= need) {
        unsigned short* NCb = (unsigned short*)d_ws;
        unsigned short* wpe = (unsigned short*)((char*)d_ws + nc_bytes);
        unsigned short* wpn = (unsigned short*)((char*)d_ws + nc_bytes + wpe_bytes);
        float* gc = (float*)((char*)d_ws + nc_bytes + wpe_bytes + wpn_bytes);

        pack2_kernel<<<7, 256, 0, stream>>>(W, b, glob, wpe, wpn, gc);
        node3_kernel<<<(Nn + 63) / 64, 256, 0, stream>>>(nodes, wpn, NCb, Nn);
        edge4_kernel<<<nblk, 256, 0, stream>>>(edges, recv, send, wpe, NCb, gc, out, E);
    } else {
        unsigned short* wp = (unsigned short*)d_ws;
        float* gc = (float*)((char*)d_ws + NFRAG * 64 * 8 * 2);
        pack_kernel<<<7, 256, 0, stream>>>(W, b, glob, wp, gc);
        edge_kernel<<<nblk, 256, 0, stream>>>(edges, nodes, recv, send, wp, gc, out, E);
    }
}

// Round 5
// 277.420 us; speedup vs baseline: 1.3578x; 1.3578x over previous
//
#include <hip/hip_runtime.h>

typedef __attribute__((ext_vector_type(8))) short short8;
typedef __attribute__((ext_vector_type(4))) float floatx4;
typedef __attribute__((ext_vector_type(4))) unsigned int uintx4;
typedef __attribute__((ext_vector_type(4))) unsigned short ushortx4;

#define D_NODE 64
#define D_OUT  64
#define ITERS 4

static __device__ __forceinline__ unsigned short f2bf(float x) {
    unsigned int u = __float_as_uint(x);
    unsigned int r = u + 0x7FFFu + ((u >> 16) & 1u);
    return (unsigned short)(r >> 16);
}

static __device__ __forceinline__ short8 cvt2(floatx4 x, floatx4 y) {
    short8 a;
    a[0] = (short)f2bf(x[0]); a[1] = (short)f2bf(x[1]);
    a[2] = (short)f2bf(x[2]); a[3] = (short)f2bf(x[3]);
    a[4] = (short)f2bf(y[0]); a[5] = (short)f2bf(y[1]);
    a[6] = (short)f2bf(y[2]); a[7] = (short)f2bf(y[3]);
    return a;
}

static __device__ __forceinline__ short8 load_cvt(const float* __restrict__ p) {
    return cvt2(*(const floatx4*)p, *(const floatx4*)(p + 4));
}

static __device__ __forceinline__ floatx4 ntload4(const float* __restrict__ p) {
    return __builtin_nontemporal_load((const floatx4*)p);
}

// Permuted W packing (see R3/R4 comments). Lane owns 16 contiguous out cols.
__global__ void pack2_kernel(const float* __restrict__ W, const float* __restrict__ b,
                             const float* __restrict__ g,
                             unsigned short* __restrict__ wpe,
                             unsigned short* __restrict__ wpn,
                             float* __restrict__ gc) {
    int tid = blockIdx.x * 256 + threadIdx.x;
    if (tid < 512) {
        int lane = tid & 63;
        int ct = (tid >> 6) & 3;
        int kstep = tid >> 8;
        int kbase = kstep * 32 + (lane >> 4) * 8;
        int col = 4 * (lane & 15) + ct;
        short8 sv;
#pragma unroll
        for (int j = 0; j < 8; ++j)
            sv[j] = (short)f2bf(W[(size_t)(kbase + j) * D_OUT + col]);
        *(short8*)(wpe + (size_t)tid * 8) = sv;
    } else if (tid < 512 + 1024) {
        int t = tid - 512;
        int lane = t & 63;
        int ct = (t >> 6) & 7;
        int kstep = t >> 9;
        int kk = kstep * 32 + (lane >> 4) * 8;
        int seg = (ct < 4) ? 64 : 128;
        int col = 4 * (lane & 15) + (ct & 3);
        short8 sv;
#pragma unroll
        for (int j = 0; j < 8; ++j)
            sv[j] = (short)f2bf(W[(size_t)(seg + kk + j) * D_OUT + col]);
        *(short8*)(wpn + (size_t)t * 8) = sv;
    } else if (tid < 512 + 1024 + 64) {
        int col = tid - 1536;
        float acc = b[col];
#pragma unroll
        for (int k = 0; k < 32; ++k)
            acc += g[k] * W[(size_t)(192 + k) * D_OUT + col];
        gc[col] = acc;
    }
}

// NC (bf16, canonical cols): NC[i][0:64] = nodes[i]@W[64:128], NC[i][64:128] = nodes[i]@W[128:192]
__global__ __launch_bounds__(256) void node3_kernel(
    const float* __restrict__ nodes, const unsigned short* __restrict__ wpn,
    unsigned short* __restrict__ NCb, int Nn) {
    const int lane = threadIdx.x & 63;
    const int wave = threadIdx.x >> 6;
    const int g = lane >> 4;
    int nbase = blockIdx.x * 64 + wave * 16;
    if (nbase >= Nn) return;

    int na = nbase + (lane & 15);
    bool valid = na < Nn;
    if (!valid) na = Nn - 1;
    const float* pn = nodes + (size_t)na * D_NODE + g * 8;
    short8 N0 = load_cvt(pn);
    short8 N1 = load_cvt(pn + 32);

    floatx4 acc[8];
#pragma unroll
    for (int ct = 0; ct < 8; ++ct) {
        short8 B0 = *(const short8*)(wpn + ((size_t)ct * 64 + lane) * 8);
        short8 B1 = *(const short8*)(wpn + ((size_t)(8 + ct) * 64 + lane) * 8);
        acc[ct] = (floatx4){0.f, 0.f, 0.f, 0.f};
        acc[ct] = __builtin_amdgcn_mfma_f32_16x16x32_bf16(B0, N0, acc[ct], 0, 0, 0);
        acc[ct] = __builtin_amdgcn_mfma_f32_16x16x32_bf16(B1, N1, acc[ct], 0, 0, 0);
    }
    if (valid) {
        unsigned short* pr = NCb + (size_t)na * 128 + 16 * g;
#pragma unroll
        for (int j = 0; j < 4; ++j) {
            ushortx4 rv, sv;
#pragma unroll
            for (int ct = 0; ct < 4; ++ct) { rv[ct] = f2bf(acc[ct][j]); sv[ct] = f2bf(acc[4 + ct][j]); }
            *(ushortx4*)(pr + 4 * j) = rv;
            *(ushortx4*)(pr + 64 + 4 * j) = sv;
        }
    }
}

__global__ __launch_bounds__(256) void edge5_kernel(
    const float* __restrict__ edges,
    const int* __restrict__ recv, const int* __restrict__ send,
    const unsigned short* __restrict__ wpe, const unsigned short* __restrict__ NCb,
    const float* __restrict__ gc, float* __restrict__ out, int E) {

    const int lane = threadIdx.x & 63;
    const int wave = threadIdx.x >> 6;
    const int g = lane >> 4;
    const int e16 = lane & 15;
    const int koff = g * 8;

    short8 Bf[8];
#pragma unroll
    for (int fi = 0; fi < 8; ++fi)
        Bf[fi] = *(const short8*)(wpe + ((size_t)fi * 64 + lane) * 8);

    floatx4 gvj[4];
#pragma unroll
    for (int j = 0; j < 4; ++j)
        gvj[j] = *(const floatx4*)(gc + 16 * g + 4 * j);

    const int base = blockIdx.x * (ITERS * 64) + wave * 16;

    int er[ITERS], ri[ITERS], si[ITERS];
#pragma unroll
    for (int it = 0; it < ITERS; ++it) {
        int r = base + it * 64 + e16;
        er[it] = (r < E) ? r : (E - 1);
        ri[it] = recv[er[it]];
        si[it] = send[er[it]];
    }

#pragma unroll
    for (int it = 0; it < ITERS; ++it) {
        // 1) gathers first (cached — want these resident in L2/L3)
        const unsigned short* pr = NCb + (size_t)ri[it] * 128 + 16 * g;
        const unsigned short* ps = NCb + (size_t)si[it] * 128 + 64 + 16 * g;
        uintx4 r0 = *(const uintx4*)pr;
        uintx4 r1 = *(const uintx4*)(pr + 8);
        uintx4 s0 = *(const uintx4*)ps;
        uintx4 s1 = *(const uintx4*)(ps + 8);

        // 2) streaming edge loads (nontemporal: don't evict NC from cache)
        const float* pe = edges + (size_t)er[it] * D_NODE + koff;
        floatx4 e0 = ntload4(pe);
        floatx4 e1 = ntload4(pe + 4);
        floatx4 e2 = ntload4(pe + 32);
        floatx4 e3 = ntload4(pe + 36);
        short8 A0 = cvt2(e0, e1);
        short8 A1 = cvt2(e2, e3);

        floatx4 acc[4];
#pragma unroll
        for (int ct = 0; ct < 4; ++ct)
            acc[ct] = (floatx4){gvj[0][ct], gvj[1][ct], gvj[2][ct], gvj[3][ct]};
#pragma unroll
        for (int ct = 0; ct < 4; ++ct) {
            acc[ct] = __builtin_amdgcn_mfma_f32_16x16x32_bf16(Bf[ct], A0, acc[ct], 0, 0, 0);
            acc[ct] = __builtin_amdgcn_mfma_f32_16x16x32_bf16(Bf[4 + ct], A1, acc[ct], 0, 0, 0);
        }

        // 3) unpack bf16 gathers and add (bf16<<16 -> f32 is exact)
#pragma unroll
        for (int d = 0; d < 4; ++d) {
            unsigned int rw0 = r0[d], sw0 = s0[d], rw1 = r1[d], sw1 = s1[d];
            float v0 = __uint_as_float(rw0 << 16) + __uint_as_float(sw0 << 16);
            float v1 = __uint_as_float(rw0 & 0xFFFF0000u) + __uint_as_float(sw0 & 0xFFFF0000u);
            float v2 = __uint_as_float(rw1 << 16) + __uint_as_float(sw1 << 16);
            float v3 = __uint_as_float(rw1 & 0xFFFF0000u) + __uint_as_float(sw1 & 0xFFFF0000u);
            int w0 = 2 * d, w1 = 2 * d + 1, w2 = 8 + 2 * d, w3 = 9 + 2 * d;
            acc[w0 & 3][w0 >> 2] += v0;
            acc[w1 & 3][w1 >> 2] += v1;
            acc[w2 & 3][w2 >> 2] += v2;
            acc[w3 & 3][w3 >> 2] += v3;
        }

        // 4) CACHED stores — L2 write-combining merges the 16B pieces into
        //    full lines (nt stores here caused 1.6x write amplification, R4).
        int row = base + it * 64 + e16;
        if (row < E) {
            float* po = out + (size_t)row * D_OUT + 16 * g;
#pragma unroll
            for (int j = 0; j < 4; ++j) {
                floatx4 v = (floatx4){acc[0][j], acc[1][j], acc[2][j], acc[3][j]};
                *(floatx4*)(po + 4 * j) = v;
            }
        }
    }
}

// ---------------- Fallback path (round-1 kernel) if ws too small ----------------

#define NKSTEP 6
#define NFRAG  (NKSTEP * 4)

__global__ void pack_kernel(const float* __restrict__ W, const float* __restrict__ b,
                            const float* __restrict__ g,
                            unsigned short* __restrict__ wp, float* __restrict__ gc) {
    int tid = blockIdx.x * 256 + threadIdx.x;
    if (tid < NFRAG * 64) {
        int lane = tid & 63;
        int ct = (tid >> 6) & 3;
        int kstep = tid >> 8;
        int kbase = kstep * 32 + (lane >> 4) * 8;
        int col = ct * 16 + (lane & 15);
        short8 sv;
#pragma unroll
        for (int j = 0; j < 8; ++j)
            sv[j] = (short)f2bf(W[(size_t)(kbase + j) * D_OUT + col]);
        *(short8*)(wp + (size_t)tid * 8) = sv;
    } else if (tid < NFRAG * 64 + 64) {
        int col = tid - NFRAG * 64;
        float acc = b[col];
#pragma unroll
        for (int k = 0; k < 32; ++k)
            acc += g[k] * W[(size_t)(192 + k) * D_OUT + col];
        gc[col] = acc;
    }
}

__global__ __launch_bounds__(256) void edge_kernel(
    const float* __restrict__ edges, const float* __restrict__ nodes,
    const int* __restrict__ recv, const int* __restrict__ send,
    const unsigned short* __restrict__ wp, const float* __restrict__ gc,
    float* __restrict__ out, int E) {

    const int lane = threadIdx.x & 63;
    const int wave = threadIdx.x >> 6;

    short8 Bf[NFRAG];
#pragma unroll
    for (int fi = 0; fi < NFRAG; ++fi)
        Bf[fi] = *(const short8*)(wp + ((size_t)fi * 64 + lane) * 8);

    const int colbase = lane & 15;
    float gv[4];
#pragma unroll
    for (int ct = 0; ct < 4; ++ct) gv[ct] = gc[ct * 16 + colbase];

    const int koff = (lane >> 4) * 8;

    for (int it = 0; it < ITERS; ++it) {
        int ebase = (blockIdx.x * ITERS + it) * 64 + wave * 16;
        if (ebase >= E) break;

        int ea = ebase + (lane & 15);
        if (ea >= E) ea = E - 1;
        int ri = recv[ea];
        int si = send[ea];

        const float* pe = edges + (size_t)ea * D_NODE + koff;
        const float* pr = nodes + (size_t)ri * D_NODE + koff;
        const float* ps = nodes + (size_t)si * D_NODE + koff;

        short8 A[NKSTEP];
        A[0] = load_cvt(pe);
        A[1] = load_cvt(pe + 32);
        A[2] = load_cvt(pr);
        A[3] = load_cvt(pr + 32);
        A[4] = load_cvt(ps);
        A[5] = load_cvt(ps + 32);

        floatx4 acc[4];
#pragma unroll
        for (int ct = 0; ct < 4; ++ct)
            acc[ct] = (floatx4){gv[ct], gv[ct], gv[ct], gv[ct]};

#pragma unroll
        for (int ks = 0; ks < NKSTEP; ++ks) {
#pragma unroll
            for (int ct = 0; ct < 4; ++ct)
                acc[ct] = __builtin_amdgcn_mfma_f32_16x16x32_bf16(
                    A[ks], Bf[ks * 4 + ct], acc[ct], 0, 0, 0);
        }

        int crow = ebase + (lane >> 4) * 4;
#pragma unroll
        for (int ct = 0; ct < 4; ++ct) {
#pragma unroll
            for (int r4 = 0; r4 < 4; ++r4) {
                int row = crow + r4;
                if (row < E)
                    out[(size_t)row * D_OUT + ct * 16 + colbase] = acc[ct][r4];
            }
        }
    }
}

extern "C" void kernel_launch(void* const* d_in, const int* in_sizes, int n_in,
                              void* d_out, int out_size, void* d_ws, size_t ws_size,
                              hipStream_t stream) {
    const float* edges = (const float*)d_in[0];
    const float* nodes = (const float*)d_in[1];
    const float* glob  = (const float*)d_in[2];
    const int*   recv  = (const int*)d_in[3];
    const int*   send  = (const int*)d_in[4];
    const float* W     = (const float*)d_in[5];
    const float* b     = (const float*)d_in[6];
    float* out = (float*)d_out;

    int E  = in_sizes[0] / D_NODE;
    int Nn = in_sizes[1] / D_NODE;

    size_t nc_bytes  = (size_t)Nn * 128 * 2;   // bf16 NC
    size_t wpe_bytes = 512 * 8 * 2;
    size_t wpn_bytes = 1024 * 8 * 2;
    size_t need = nc_bytes + wpe_bytes + wpn_bytes + 256;

    int nblk = (E + ITERS * 64 - 1) / (ITERS * 64);

    if (ws_size >= need) {
        unsigned short* NCb = (unsigned short*)d_ws;
        unsigned short* wpe = (unsigned short*)((char*)d_ws + nc_bytes);
        unsigned short* wpn = (unsigned short*)((char*)d_ws + nc_bytes + wpe_bytes);
        float* gc = (float*)((char*)d_ws + nc_bytes + wpe_bytes + wpn_bytes);

        pack2_kernel<<<7, 256, 0, stream>>>(W, b, glob, wpe, wpn, gc);
        node3_kernel<<<(Nn + 63) / 64, 256, 0, stream>>>(nodes, wpn, NCb, Nn);
        edge5_kernel<<<nblk, 256, 0, stream>>>(edges, recv, send, wpe, NCb, gc, out, E);
    } else {
        unsigned short* wp = (unsigned short*)d_ws;
        float* gc = (float*)((char*)d_ws + NFRAG * 64 * 8 * 2);
        pack_kernel<<<7, 256, 0, stream>>>(W, b, glob, wp, gc);
        edge_kernel<<<nblk, 256, 0, stream>>>(edges, nodes, recv, send, wp, gc, out, E);
    }
}

// Round 6
// 257.128 us; speedup vs baseline: 1.4649x; 1.0789x over previous
//
#include <hip/hip_runtime.h>

typedef __attribute__((ext_vector_type(8))) short short8;
typedef __attribute__((ext_vector_type(4))) float floatx4;
typedef __attribute__((ext_vector_type(4))) unsigned int uintx4;
typedef __attribute__((ext_vector_type(4))) unsigned short ushortx4;

#define D_NODE 64
#define D_OUT  64

static __device__ __forceinline__ unsigned short f2bf(float x) {
    unsigned int u = __float_as_uint(x);
    unsigned int r = u + 0x7FFFu + ((u >> 16) & 1u);
    return (unsigned short)(r >> 16);
}

static __device__ __forceinline__ short8 cvt2(floatx4 x, floatx4 y) {
    short8 a;
    a[0] = (short)f2bf(x[0]); a[1] = (short)f2bf(x[1]);
    a[2] = (short)f2bf(x[2]); a[3] = (short)f2bf(x[3]);
    a[4] = (short)f2bf(y[0]); a[5] = (short)f2bf(y[1]);
    a[6] = (short)f2bf(y[2]); a[7] = (short)f2bf(y[3]);
    return a;
}

static __device__ __forceinline__ short8 load_cvt(const float* __restrict__ p) {
    return cvt2(*(const floatx4*)p, *(const floatx4*)(p + 4));
}

static __device__ __forceinline__ floatx4 ntload4(const float* __restrict__ p) {
    return __builtin_nontemporal_load((const floatx4*)p);
}

// Permuted W packing (see R3 comments). Lane owns 16 contiguous out cols.
__global__ void pack2_kernel(const float* __restrict__ W, const float* __restrict__ b,
                             const float* __restrict__ g,
                             unsigned short* __restrict__ wpe,
                             unsigned short* __restrict__ wpn,
                             float* __restrict__ gc) {
    int tid = blockIdx.x * 256 + threadIdx.x;
    if (tid < 512) {
        int lane = tid & 63;
        int ct = (tid >> 6) & 3;
        int kstep = tid >> 8;
        int kbase = kstep * 32 + (lane >> 4) * 8;
        int col = 4 * (lane & 15) + ct;
        short8 sv;
#pragma unroll
        for (int j = 0; j < 8; ++j)
            sv[j] = (short)f2bf(W[(size_t)(kbase + j) * D_OUT + col]);
        *(short8*)(wpe + (size_t)tid * 8) = sv;
    } else if (tid < 512 + 1024) {
        int t = tid - 512;
        int lane = t & 63;
        int ct = (t >> 6) & 7;
        int kstep = t >> 9;
        int kk = kstep * 32 + (lane >> 4) * 8;
        int seg = (ct < 4) ? 64 : 128;
        int col = 4 * (lane & 15) + (ct & 3);
        short8 sv;
#pragma unroll
        for (int j = 0; j < 8; ++j)
            sv[j] = (short)f2bf(W[(size_t)(seg + kk + j) * D_OUT + col]);
        *(short8*)(wpn + (size_t)t * 8) = sv;
    } else if (tid < 512 + 1024 + 64) {
        int col = tid - 1536;
        float acc = b[col];
#pragma unroll
        for (int k = 0; k < 32; ++k)
            acc += g[k] * W[(size_t)(192 + k) * D_OUT + col];
        gc[col] = acc;
    }
}

// NC (bf16): NC[i][0:64] = nodes[i]@W[64:128], NC[i][64:128] = nodes[i]@W[128:192]
__global__ __launch_bounds__(256) void node3_kernel(
    const float* __restrict__ nodes, const unsigned short* __restrict__ wpn,
    unsigned short* __restrict__ NCb, int Nn) {
    const int lane = threadIdx.x & 63;
    const int wave = threadIdx.x >> 6;
    const int g = lane >> 4;
    int nbase = blockIdx.x * 64 + wave * 16;
    if (nbase >= Nn) return;

    int na = nbase + (lane & 15);
    bool valid = na < Nn;
    if (!valid) na = Nn - 1;
    const float* pn = nodes + (size_t)na * D_NODE + g * 8;
    short8 N0 = load_cvt(pn);
    short8 N1 = load_cvt(pn + 32);

    floatx4 acc[8];
#pragma unroll
    for (int ct = 0; ct < 8; ++ct) {
        short8 B0 = *(const short8*)(wpn + ((size_t)ct * 64 + lane) * 8);
        short8 B1 = *(const short8*)(wpn + ((size_t)(8 + ct) * 64 + lane) * 8);
        acc[ct] = (floatx4){0.f, 0.f, 0.f, 0.f};
        acc[ct] = __builtin_amdgcn_mfma_f32_16x16x32_bf16(B0, N0, acc[ct], 0, 0, 0);
        acc[ct] = __builtin_amdgcn_mfma_f32_16x16x32_bf16(B1, N1, acc[ct], 0, 0, 0);
    }
    if (valid) {
        unsigned short* pr = NCb + (size_t)na * 128 + 16 * g;
#pragma unroll
        for (int j = 0; j < 4; ++j) {
            ushortx4 rv, sv;
#pragma unroll
            for (int ct = 0; ct < 4; ++ct) { rv[ct] = f2bf(acc[ct][j]); sv[ct] = f2bf(acc[4 + ct][j]); }
            *(ushortx4*)(pr + 4 * j) = rv;
            *(ushortx4*)(pr + 64 + 4 * j) = sv;
        }
    }
}

struct TileData {
    floatx4 e0, e1, e2, e3;   // raw edge features (lane's 32 floats)
    uintx4 r0, r1, s0, s1;    // bf16 NC gathers (recv 32B, send 32B)
};

static __device__ __forceinline__ void load_tile(
    const float* __restrict__ edges, const unsigned short* __restrict__ NCb,
    int er, int ri, int si, int koff, int g, TileData& td) {
    const float* pe = edges + (size_t)er * D_NODE + koff;
    td.e0 = ntload4(pe);
    td.e1 = ntload4(pe + 4);
    td.e2 = ntload4(pe + 32);
    td.e3 = ntload4(pe + 36);
    const unsigned short* pr = NCb + (size_t)ri * 128 + 16 * g;
    td.r0 = *(const uintx4*)pr;
    td.r1 = *(const uintx4*)(pr + 8);
    const unsigned short* ps = NCb + (size_t)si * 128 + 64 + 16 * g;
    td.s0 = *(const uintx4*)ps;
    td.s1 = *(const uintx4*)(ps + 8);
}

static __device__ __forceinline__ void compute_store(
    const TileData& td, const short8* __restrict__ Bf, const floatx4* __restrict__ gvj,
    float* __restrict__ out, int row, int g, int E) {
    short8 A0 = cvt2(td.e0, td.e1);
    short8 A1 = cvt2(td.e2, td.e3);

    floatx4 acc[4];
#pragma unroll
    for (int ct = 0; ct < 4; ++ct)
        acc[ct] = (floatx4){gvj[0][ct], gvj[1][ct], gvj[2][ct], gvj[3][ct]};
#pragma unroll
    for (int ct = 0; ct < 4; ++ct) {
        acc[ct] = __builtin_amdgcn_mfma_f32_16x16x32_bf16(Bf[ct], A0, acc[ct], 0, 0, 0);
        acc[ct] = __builtin_amdgcn_mfma_f32_16x16x32_bf16(Bf[4 + ct], A1, acc[ct], 0, 0, 0);
    }

    uintx4 rr0 = td.r0, rr1 = td.r1, ss0 = td.s0, ss1 = td.s1;
#pragma unroll
    for (int d = 0; d < 4; ++d) {
        unsigned int rw0 = rr0[d], sw0 = ss0[d], rw1 = rr1[d], sw1 = ss1[d];
        float v0 = __uint_as_float(rw0 << 16) + __uint_as_float(sw0 << 16);
        float v1 = __uint_as_float(rw0 & 0xFFFF0000u) + __uint_as_float(sw0 & 0xFFFF0000u);
        float v2 = __uint_as_float(rw1 << 16) + __uint_as_float(sw1 << 16);
        float v3 = __uint_as_float(rw1 & 0xFFFF0000u) + __uint_as_float(sw1 & 0xFFFF0000u);
        int w0 = 2 * d, w1 = 2 * d + 1, w2 = 8 + 2 * d, w3 = 9 + 2 * d;
        acc[w0 & 3][w0 >> 2] += v0;
        acc[w1 & 3][w1 >> 2] += v1;
        acc[w2 & 3][w2 >> 2] += v2;
        acc[w3 & 3][w3 >> 2] += v3;
    }

    if (row < E) {
        float* po = out + (size_t)row * D_OUT + 16 * g;
#pragma unroll
        for (int j = 0; j < 4; ++j) {
            floatx4 v = (floatx4){acc[0][j], acc[1][j], acc[2][j], acc[3][j]};
            *(floatx4*)(po + 4 * j) = v;
        }
    }
}

// Persistent grid-stride kernel, 3-stage pipeline:
//   stage k: [issue loads for tile k+1] [prefetch idx for tile k+2] [compute+store tile k]
__global__ __launch_bounds__(256) void edge6_kernel(
    const float* __restrict__ edges,
    const int* __restrict__ recv, const int* __restrict__ send,
    const unsigned short* __restrict__ wpe, const unsigned short* __restrict__ NCb,
    const float* __restrict__ gc, float* __restrict__ out, int E, int T) {

    const int lane = threadIdx.x & 63;
    const int wave = threadIdx.x >> 6;
    const int g = lane >> 4;
    const int e16 = lane & 15;
    const int koff = g * 8;
    const int stride = gridDim.x;
    const int slot = wave * 16 + e16;

    short8 Bf[8];
#pragma unroll
    for (int fi = 0; fi < 8; ++fi)
        Bf[fi] = *(const short8*)(wpe + ((size_t)fi * 64 + lane) * 8);

    floatx4 gvj[4];
#pragma unroll
    for (int j = 0; j < 4; ++j)
        gvj[j] = *(const floatx4*)(gc + 16 * g + 4 * j);

    const int t0 = blockIdx.x;

    // prologue: idx for tile 0 and tile 1, then data for tile 0
    int er_c, ri_c, si_c;
    {
        int r = t0 * 64 + slot;
        er_c = (r < E) ? r : (E - 1);
        ri_c = recv[er_c];
        si_c = send[er_c];
    }
    int er_n = er_c, ri_n = ri_c, si_n = si_c;
    if (T > 1) {
        int r = (t0 + stride) * 64 + slot;
        er_n = (r < E) ? r : (E - 1);
        ri_n = recv[er_n];
        si_n = send[er_n];
    }

    TileData A_;
    load_tile(edges, NCb, er_c, ri_c, si_c, koff, g, A_);

    for (int k = 0; k < T; ++k) {
        // (a) issue next tile's data loads (indices already arrived)
        TileData B_;
        if (k + 1 < T)
            load_tile(edges, NCb, er_n, ri_n, si_n, koff, g, B_);

        // (b) prefetch indices for tile k+2
        int er2 = er_n, ri2 = ri_n, si2 = si_n;
        if (k + 2 < T) {
            int r = (t0 + (k + 2) * stride) * 64 + slot;
            er2 = (r < E) ? r : (E - 1);
            ri2 = recv[er2];
            si2 = send[er2];
        }

        // (c) compute + store current tile (loads issued >=1 full tile ago)
        int row = (t0 + k * stride) * 64 + slot;
        compute_store(A_, Bf, gvj, out, row, g, E);

        // rotate
        er_n = er2; ri_n = ri2; si_n = si2;
        if (k + 1 < T) A_ = B_;
    }
}

// ---------------- Fallback path (round-1 kernel) if ws too small ----------------

#define NKSTEP 6
#define NFRAG  (NKSTEP * 4)
#define ITERS 4

__global__ void pack_kernel(const float* __restrict__ W, const float* __restrict__ b,
                            const float* __restrict__ g,
                            unsigned short* __restrict__ wp, float* __restrict__ gc) {
    int tid = blockIdx.x * 256 + threadIdx.x;
    if (tid < NFRAG * 64) {
        int lane = tid & 63;
        int ct = (tid >> 6) & 3;
        int kstep = tid >> 8;
        int kbase = kstep * 32 + (lane >> 4) * 8;
        int col = ct * 16 + (lane & 15);
        short8 sv;
#pragma unroll
        for (int j = 0; j < 8; ++j)
            sv[j] = (short)f2bf(W[(size_t)(kbase + j) * D_OUT + col]);
        *(short8*)(wp + (size_t)tid * 8) = sv;
    } else if (tid < NFRAG * 64 + 64) {
        int col = tid - NFRAG * 64;
        float acc = b[col];
#pragma unroll
        for (int k = 0; k < 32; ++k)
            acc += g[k] * W[(size_t)(192 + k) * D_OUT + col];
        gc[col] = acc;
    }
}

__global__ __launch_bounds__(256) void edge_kernel(
    const float* __restrict__ edges, const float* __restrict__ nodes,
    const int* __restrict__ recv, const int* __restrict__ send,
    const unsigned short* __restrict__ wp, const float* __restrict__ gc,
    float* __restrict__ out, int E) {

    const int lane = threadIdx.x & 63;
    const int wave = threadIdx.x >> 6;

    short8 Bf[NFRAG];
#pragma unroll
    for (int fi = 0; fi < NFRAG; ++fi)
        Bf[fi] = *(const short8*)(wp + ((size_t)fi * 64 + lane) * 8);

    const int colbase = lane & 15;
    float gv[4];
#pragma unroll
    for (int ct = 0; ct < 4; ++ct) gv[ct] = gc[ct * 16 + colbase];

    const int koff = (lane >> 4) * 8;

    for (int it = 0; it < ITERS; ++it) {
        int ebase = (blockIdx.x * ITERS + it) * 64 + wave * 16;
        if (ebase >= E) break;

        int ea = ebase + (lane & 15);
        if (ea >= E) ea = E - 1;
        int ri = recv[ea];
        int si = send[ea];

        const float* pe = edges + (size_t)ea * D_NODE + koff;
        const float* pr = nodes + (size_t)ri * D_NODE + koff;
        const float* ps = nodes + (size_t)si * D_NODE + koff;

        short8 A[NKSTEP];
        A[0] = load_cvt(pe);
        A[1] = load_cvt(pe + 32);
        A[2] = load_cvt(pr);
        A[3] = load_cvt(pr + 32);
        A[4] = load_cvt(ps);
        A[5] = load_cvt(ps + 32);

        floatx4 acc[4];
#pragma unroll
        for (int ct = 0; ct < 4; ++ct)
            acc[ct] = (floatx4){gv[ct], gv[ct], gv[ct], gv[ct]};

#pragma unroll
        for (int ks = 0; ks < NKSTEP; ++ks) {
#pragma unroll
            for (int ct = 0; ct < 4; ++ct)
                acc[ct] = __builtin_amdgcn_mfma_f32_16x16x32_bf16(
                    A[ks], Bf[ks * 4 + ct], acc[ct], 0, 0, 0);
        }

        int crow = ebase + (lane >> 4) * 4;
#pragma unroll
        for (int ct = 0; ct < 4; ++ct) {
#pragma unroll
            for (int r4 = 0; r4 < 4; ++r4) {
                int row = crow + r4;
                if (row < E)
                    out[(size_t)row * D_OUT + ct * 16 + colbase] = acc[ct][r4];
            }
        }
    }
}

extern "C" void kernel_launch(void* const* d_in, const int* in_sizes, int n_in,
                              void* d_out, int out_size, void* d_ws, size_t ws_size,
                              hipStream_t stream) {
    const float* edges = (const float*)d_in[0];
    const float* nodes = (const float*)d_in[1];
    const float* glob  = (const float*)d_in[2];
    const int*   recv  = (const int*)d_in[3];
    const int*   send  = (const int*)d_in[4];
    const float* W     = (const float*)d_in[5];
    const float* b     = (const float*)d_in[6];
    float* out = (float*)d_out;

    int E  = in_sizes[0] / D_NODE;
    int Nn = in_sizes[1] / D_NODE;

    size_t nc_bytes  = (size_t)Nn * 128 * 2;   // bf16 NC
    size_t wpe_bytes = 512 * 8 * 2;
    size_t wpn_bytes = 1024 * 8 * 2;
    size_t need = nc_bytes + wpe_bytes + wpn_bytes + 256;

    if (ws_size >= need) {
        unsigned short* NCb = (unsigned short*)d_ws;
        unsigned short* wpe = (unsigned short*)((char*)d_ws + nc_bytes);
        unsigned short* wpn = (unsigned short*)((char*)d_ws + nc_bytes + wpe_bytes);
        float* gc = (float*)((char*)d_ws + nc_bytes + wpe_bytes + wpn_bytes);

        pack2_kernel<<<7, 256, 0, stream>>>(W, b, glob, wpe, wpn, gc);
        node3_kernel<<<(Nn + 63) / 64, 256, 0, stream>>>(nodes, wpn, NCb, Nn);

        int NT = (E + 63) / 64;                 // 64-edge tiles
        int grid = (NT < 2500) ? NT : 2500;     // persistent-ish grid
        int T = (NT + grid - 1) / grid;         // tiles per block
        edge6_kernel<<<grid, 256, 0, stream>>>(edges, recv, send, wpe, NCb, gc, out, E, T);
    } else {
        unsigned short* wp = (unsigned short*)d_ws;
        float* gc = (float*)((char*)d_ws + NFRAG * 64 * 8 * 2);
        pack_kernel<<<7, 256, 0, stream>>>(W, b, glob, wp, gc);
        int nblk = (E + ITERS * 64 - 1) / (ITERS * 64);
        edge_kernel<<<nblk, 256, 0, stream>>>(edges, nodes, recv, send, wp, gc, out, E);
    }
}

// Round 7
// 206.590 us; speedup vs baseline: 1.8233x; 1.2446x over previous
//
#include <hip/hip_runtime.h>

typedef __attribute__((ext_vector_type(8))) short short8;
typedef __attribute__((ext_vector_type(4))) float floatx4;

#define D_NODE 64
#define D_OUT  64

static __device__ __forceinline__ unsigned short f2bf(float x) {
    unsigned int u = __float_as_uint(x);
    unsigned int r = u + 0x7FFFu + ((u >> 16) & 1u);
    return (unsigned short)(r >> 16);
}

static __device__ __forceinline__ short8 cvt2(floatx4 x, floatx4 y) {
    short8 a;
    a[0] = (short)f2bf(x[0]); a[1] = (short)f2bf(x[1]);
    a[2] = (short)f2bf(x[2]); a[3] = (short)f2bf(x[3]);
    a[4] = (short)f2bf(y[0]); a[5] = (short)f2bf(y[1]);
    a[6] = (short)f2bf(y[2]); a[7] = (short)f2bf(y[3]);
    return a;
}

static __device__ __forceinline__ short8 load_cvt(const float* __restrict__ p) {
    return cvt2(*(const floatx4*)p, *(const floatx4*)(p + 4));
}

static __device__ __forceinline__ floatx4 ntload4(const float* __restrict__ p) {
    return __builtin_nontemporal_load((const floatx4*)p);
}

// LDS swizzle: byte offset of (row r 0..15, 16B-chunk ch 0..15) inside a 4KB tile.
// XOR spreads the 16B slots across banks: conflict floor (8 lanes/slot) on both
// the MFMA-layout write and the stream-layout read.
static __device__ __forceinline__ int sz(int r, int ch) {
    return (r << 8) + (((ch << 4)) ^ ((r & 7) << 4));
}

// Permuted W packing (R3): lane owns 16 contiguous out cols.
__global__ void pack2_kernel(const float* __restrict__ W, const float* __restrict__ b,
                             const float* __restrict__ g,
                             unsigned short* __restrict__ wpe,
                             unsigned short* __restrict__ wpn,
                             float* __restrict__ gc) {
    int tid = blockIdx.x * 256 + threadIdx.x;
    if (tid < 512) {
        int lane = tid & 63;
        int ct = (tid >> 6) & 3;
        int kstep = tid >> 8;
        int kbase = kstep * 32 + (lane >> 4) * 8;
        int col = 4 * (lane & 15) + ct;
        short8 sv;
#pragma unroll
        for (int j = 0; j < 8; ++j)
            sv[j] = (short)f2bf(W[(size_t)(kbase + j) * D_OUT + col]);
        *(short8*)(wpe + (size_t)tid * 8) = sv;
    } else if (tid < 512 + 1024) {
        int t = tid - 512;
        int lane = t & 63;
        int ct = (t >> 6) & 7;
        int kstep = t >> 9;
        int kk = kstep * 32 + (lane >> 4) * 8;
        int seg = (ct < 4) ? 64 : 128;
        int col = 4 * (lane & 15) + (ct & 3);
        short8 sv;
#pragma unroll
        for (int j = 0; j < 8; ++j)
            sv[j] = (short)f2bf(W[(size_t)(seg + kk + j) * D_OUT + col]);
        *(short8*)(wpn + (size_t)t * 8) = sv;
    } else if (tid < 512 + 1024 + 64) {
        int col = tid - 1536;
        float acc = b[col];
#pragma unroll
        for (int k = 0; k < 32; ++k)
            acc += g[k] * W[(size_t)(192 + k) * D_OUT + col];
        gc[col] = acc;
    }
}

// NC (bf16): NC[i][0:64] = nodes[i]@W[64:128], NC[i][64:128] = nodes[i]@W[128:192]
__global__ __launch_bounds__(256) void node3_kernel(
    const float* __restrict__ nodes, const unsigned short* __restrict__ wpn,
    unsigned short* __restrict__ NCb, int Nn) {
    const int lane = threadIdx.x & 63;
    const int wave = threadIdx.x >> 6;
    const int g = lane >> 4;
    int nbase = blockIdx.x * 64 + wave * 16;
    if (nbase >= Nn) return;

    int na = nbase + (lane & 15);
    bool valid = na < Nn;
    if (!valid) na = Nn - 1;
    const float* pn = nodes + (size_t)na * D_NODE + g * 8;
    short8 N0 = load_cvt(pn);
    short8 N1 = load_cvt(pn + 32);

    floatx4 acc[8];
#pragma unroll
    for (int ct = 0; ct < 8; ++ct) {
        short8 B0 = *(const short8*)(wpn + ((size_t)ct * 64 + lane) * 8);
        short8 B1 = *(const short8*)(wpn + ((size_t)(8 + ct) * 64 + lane) * 8);
        acc[ct] = (floatx4){0.f, 0.f, 0.f, 0.f};
        acc[ct] = __builtin_amdgcn_mfma_f32_16x16x32_bf16(B0, N0, acc[ct], 0, 0, 0);
        acc[ct] = __builtin_amdgcn_mfma_f32_16x16x32_bf16(B1, N1, acc[ct], 0, 0, 0);
    }
    if (valid) {
        unsigned short* pr = NCb + (size_t)na * 128 + 16 * g;
#pragma unroll
        for (int j = 0; j < 4; ++j) {
            unsigned short rv[4], sv[4];
#pragma unroll
            for (int ct = 0; ct < 4; ++ct) { rv[ct] = f2bf(acc[ct][j]); sv[ct] = f2bf(acc[4 + ct][j]); }
            *(uint2*)(pr + 4 * j) = *(uint2*)rv;
            *(uint2*)(pr + 64 + 4 * j) = *(uint2*)sv;
        }
    }
}

struct EdgeRegs { floatx4 e0, e1, e2, e3; };
struct GathRegs { uint2 r0, r1, r2, r3, s0, s1, s2, s3; };
struct IdxRegs  { int r0, r1, r2, r3, s0, s1, s2, s3; };

__global__ __launch_bounds__(256) void edge7_kernel(
    const float* __restrict__ edges,
    const int* __restrict__ recv, const int* __restrict__ send,
    const unsigned short* __restrict__ wpe, const unsigned short* __restrict__ NCb,
    const float* __restrict__ gc, float* __restrict__ out, int E, int T) {

    __shared__ float lds[4][1024];   // 4KB per wave, private (no barriers)

    const int lane = threadIdx.x & 63;
    const int wave = threadIdx.x >> 6;
    const int g = lane >> 4;     // MFMA k-group / col-group
    const int e16 = lane & 15;   // MFMA edge-row within tile
    const int c = lane & 15;     // stream: 16B chunk id (cols [4c,4c+4))
    const int lr = lane >> 4;    // stream: row-subindex within a 1KB step
    const int koff = g * 8;
    const int stride = gridDim.x;
    char* buf = (char*)&lds[wave][0];

    short8 Bf[8];
#pragma unroll
    for (int fi = 0; fi < 8; ++fi)
        Bf[fi] = *(const short8*)(wpe + ((size_t)fi * 64 + lane) * 8);

    const floatx4 gc4 = *(const floatx4*)(gc + 4 * c);   // bias+globals, cols [4c,4c+4)

    const int t0 = blockIdx.x;
    // per-wave tile base for tile k: rows [(t0+k*stride)*64 + wave*16, +16)
#define TBASE(k) ((t0 + (k) * stride) * 64 + wave * 16)

    // ---- helpers as lambdas (static layout, no runtime-indexed arrays) ----
    auto load_idx = [&](int b) {
        IdxRegs I;
        int q0 = b + 0 + lr;  q0 = (q0 < E) ? q0 : E - 1;
        int q1 = b + 4 + lr;  q1 = (q1 < E) ? q1 : E - 1;
        int q2 = b + 8 + lr;  q2 = (q2 < E) ? q2 : E - 1;
        int q3 = b + 12 + lr; q3 = (q3 < E) ? q3 : E - 1;
        I.r0 = recv[q0]; I.r1 = recv[q1]; I.r2 = recv[q2]; I.r3 = recv[q3];
        I.s0 = send[q0]; I.s1 = send[q1]; I.s2 = send[q2]; I.s3 = send[q3];
        return I;
    };
    auto load_edges = [&](int b) {
        EdgeRegs Er;
        int er = b + e16; er = (er < E) ? er : E - 1;
        const float* pe = edges + (size_t)er * D_NODE + koff;
        Er.e0 = ntload4(pe);
        Er.e1 = ntload4(pe + 4);
        Er.e2 = ntload4(pe + 32);
        Er.e3 = ntload4(pe + 36);
        return Er;
    };
    auto load_gath = [&](const IdxRegs& I) {
        GathRegs G;
        G.r0 = *(const uint2*)(NCb + (size_t)I.r0 * 128 + 4 * c);
        G.r1 = *(const uint2*)(NCb + (size_t)I.r1 * 128 + 4 * c);
        G.r2 = *(const uint2*)(NCb + (size_t)I.r2 * 128 + 4 * c);
        G.r3 = *(const uint2*)(NCb + (size_t)I.r3 * 128 + 4 * c);
        G.s0 = *(const uint2*)(NCb + (size_t)I.s0 * 128 + 64 + 4 * c);
        G.s1 = *(const uint2*)(NCb + (size_t)I.s1 * 128 + 64 + 4 * c);
        G.s2 = *(const uint2*)(NCb + (size_t)I.s2 * 128 + 64 + 4 * c);
        G.s3 = *(const uint2*)(NCb + (size_t)I.s3 * 128 + 64 + 4 * c);
        return G;
    };
    auto addg = [&](floatx4 v, uint2 r, uint2 s) {
        v[0] += __uint_as_float(r.x << 16) + __uint_as_float(s.x << 16);
        v[1] += __uint_as_float(r.x & 0xFFFF0000u) + __uint_as_float(s.x & 0xFFFF0000u);
        v[2] += __uint_as_float(r.y << 16) + __uint_as_float(s.y << 16);
        v[3] += __uint_as_float(r.y & 0xFFFF0000u) + __uint_as_float(s.y & 0xFFFF0000u);
        return v;
    };

    auto compute_store = [&](int b0, const EdgeRegs& Er, const GathRegs& G) {
        short8 A0 = cvt2(Er.e0, Er.e1);
        short8 A1 = cvt2(Er.e2, Er.e3);

        floatx4 acc0 = {0,0,0,0}, acc1 = {0,0,0,0}, acc2 = {0,0,0,0}, acc3 = {0,0,0,0};
        acc0 = __builtin_amdgcn_mfma_f32_16x16x32_bf16(Bf[0], A0, acc0, 0, 0, 0);
        acc1 = __builtin_amdgcn_mfma_f32_16x16x32_bf16(Bf[1], A0, acc1, 0, 0, 0);
        acc2 = __builtin_amdgcn_mfma_f32_16x16x32_bf16(Bf[2], A0, acc2, 0, 0, 0);
        acc3 = __builtin_amdgcn_mfma_f32_16x16x32_bf16(Bf[3], A0, acc3, 0, 0, 0);
        acc0 = __builtin_amdgcn_mfma_f32_16x16x32_bf16(Bf[4], A1, acc0, 0, 0, 0);
        acc1 = __builtin_amdgcn_mfma_f32_16x16x32_bf16(Bf[5], A1, acc1, 0, 0, 0);
        acc2 = __builtin_amdgcn_mfma_f32_16x16x32_bf16(Bf[6], A1, acc2, 0, 0, 0);
        acc3 = __builtin_amdgcn_mfma_f32_16x16x32_bf16(Bf[7], A1, acc3, 0, 0, 0);

        // acc{ct}[j] = out col 16g+4j+ct of row e16  ->  chunk 4g+j of row e16
#pragma unroll
        for (int j = 0; j < 4; ++j) {
            floatx4 v = (floatx4){acc0[j], acc1[j], acc2[j], acc3[j]};
            *(floatx4*)(buf + sz(e16, 4 * g + j)) = v;
        }

        // stream out: step i covers rows b0+4i..+3, 1KB fully contiguous
        {
            floatx4 v0 = *(const floatx4*)(buf + sz(0 + lr, c));
            int row = b0 + 0 + lr;
            v0 = addg(v0 + gc4, G.r0, G.s0);
            if (row < E) *(floatx4*)(out + (size_t)row * D_OUT + 4 * c) = v0;
        }
        {
            floatx4 v1 = *(const floatx4*)(buf + sz(4 + lr, c));
            int row = b0 + 4 + lr;
            v1 = addg(v1 + gc4, G.r1, G.s1);
            if (row < E) *(floatx4*)(out + (size_t)row * D_OUT + 4 * c) = v1;
        }
        {
            floatx4 v2 = *(const floatx4*)(buf + sz(8 + lr, c));
            int row = b0 + 8 + lr;
            v2 = addg(v2 + gc4, G.r2, G.s2);
            if (row < E) *(floatx4*)(out + (size_t)row * D_OUT + 4 * c) = v2;
        }
        {
            floatx4 v3 = *(const floatx4*)(buf + sz(12 + lr, c));
            int row = b0 + 12 + lr;
            v3 = addg(v3 + gc4, G.r3, G.s3);
            if (row < E) *(floatx4*)(out + (size_t)row * D_OUT + 4 * c) = v3;
        }
    };

    // ---- prologue ----
    IdxRegs I0 = load_idx(TBASE(0));
    IdxRegs In = (T > 1) ? load_idx(TBASE(1)) : I0;
    EdgeRegs Ecur = load_edges(TBASE(0));
    GathRegs Gcur = load_gath(I0);

    for (int k = 0; k < T; ++k) {
        EdgeRegs Enext;
        GathRegs Gnext;
        if (k + 1 < T) {                     // (a) issue next tile's data loads
            Enext = load_edges(TBASE(k + 1));
            Gnext = load_gath(In);
        }
        IdxRegs I2 = In;
        if (k + 2 < T)                       // (b) prefetch idx 2 tiles ahead
            I2 = load_idx(TBASE(k + 2));

        compute_store(TBASE(k), Ecur, Gcur); // (c) compute + LDS-transposed store

        if (k + 1 < T) { Ecur = Enext; Gcur = Gnext; }
        In = I2;
    }
#undef TBASE
}

// ---------------- Fallback path (round-1 kernel) if ws too small ----------------

#define NKSTEP 6
#define NFRAG  (NKSTEP * 4)
#define ITERS 4

__global__ void pack_kernel(const float* __restrict__ W, const float* __restrict__ b,
                            const float* __restrict__ g,
                            unsigned short* __restrict__ wp, float* __restrict__ gc) {
    int tid = blockIdx.x * 256 + threadIdx.x;
    if (tid < NFRAG * 64) {
        int lane = tid & 63;
        int ct = (tid >> 6) & 3;
        int kstep = tid >> 8;
        int kbase = kstep * 32 + (lane >> 4) * 8;
        int col = ct * 16 + (lane & 15);
        short8 sv;
#pragma unroll
        for (int j = 0; j < 8; ++j)
            sv[j] = (short)f2bf(W[(size_t)(kbase + j) * D_OUT + col]);
        *(short8*)(wp + (size_t)tid * 8) = sv;
    } else if (tid < NFRAG * 64 + 64) {
        int col = tid - NFRAG * 64;
        float acc = b[col];
#pragma unroll
        for (int k = 0; k < 32; ++k)
            acc += g[k] * W[(size_t)(192 + k) * D_OUT + col];
        gc[col] = acc;
    }
}

__global__ __launch_bounds__(256) void edge_kernel(
    const float* __restrict__ edges, const float* __restrict__ nodes,
    const int* __restrict__ recv, const int* __restrict__ send,
    const unsigned short* __restrict__ wp, const float* __restrict__ gc,
    float* __restrict__ out, int E) {

    const int lane = threadIdx.x & 63;
    const int wave = threadIdx.x >> 6;

    short8 Bf[NFRAG];
#pragma unroll
    for (int fi = 0; fi < NFRAG; ++fi)
        Bf[fi] = *(const short8*)(wp + ((size_t)fi * 64 + lane) * 8);

    const int colbase = lane & 15;
    float gv[4];
#pragma unroll
    for (int ct = 0; ct < 4; ++ct) gv[ct] = gc[ct * 16 + colbase];

    const int koff = (lane >> 4) * 8;

    for (int it = 0; it < ITERS; ++it) {
        int ebase = (blockIdx.x * ITERS + it) * 64 + wave * 16;
        if (ebase >= E) break;

        int ea = ebase + (lane & 15);
        if (ea >= E) ea = E - 1;
        int ri = recv[ea];
        int si = send[ea];

        const float* pe = edges + (size_t)ea * D_NODE + koff;
        const float* pr = nodes + (size_t)ri * D_NODE + koff;
        const float* ps = nodes + (size_t)si * D_NODE + koff;

        short8 A[NKSTEP];
        A[0] = load_cvt(pe);
        A[1] = load_cvt(pe + 32);
        A[2] = load_cvt(pr);
        A[3] = load_cvt(pr + 32);
        A[4] = load_cvt(ps);
        A[5] = load_cvt(ps + 32);

        floatx4 acc[4];
#pragma unroll
        for (int ct = 0; ct < 4; ++ct)
            acc[ct] = (floatx4){gv[ct], gv[ct], gv[ct], gv[ct]};

#pragma unroll
        for (int ks = 0; ks < NKSTEP; ++ks) {
#pragma unroll
            for (int ct = 0; ct < 4; ++ct)
                acc[ct] = __builtin_amdgcn_mfma_f32_16x16x32_bf16(
                    A[ks], Bf[ks * 4 + ct], acc[ct], 0, 0, 0);
        }

        int crow = ebase + (lane >> 4) * 4;
#pragma unroll
        for (int ct = 0; ct < 4; ++ct) {
#pragma unroll
            for (int r4 = 0; r4 < 4; ++r4) {
                int row = crow + r4;
                if (row < E)
                    out[(size_t)row * D_OUT + ct * 16 + colbase] = acc[ct][r4];
            }
        }
    }
}

extern "C" void kernel_launch(void* const* d_in, const int* in_sizes, int n_in,
                              void* d_out, int out_size, void* d_ws, size_t ws_size,
                              hipStream_t stream) {
    const float* edges = (const float*)d_in[0];
    const float* nodes = (const float*)d_in[1];
    const float* glob  = (const float*)d_in[2];
    const int*   recv  = (const int*)d_in[3];
    const int*   send  = (const int*)d_in[4];
    const float* W     = (const float*)d_in[5];
    const float* b     = (const float*)d_in[6];
    float* out = (float*)d_out;

    int E  = in_sizes[0] / D_NODE;
    int Nn = in_sizes[1] / D_NODE;

    size_t nc_bytes  = (size_t)Nn * 128 * 2;   // bf16 NC
    size_t wpe_bytes = 512 * 8 * 2;
    size_t wpn_bytes = 1024 * 8 * 2;
    size_t need = nc_bytes + wpe_bytes + wpn_bytes + 256;

    if (ws_size >= need) {
        unsigned short* NCb = (unsigned short*)d_ws;
        unsigned short* wpe = (unsigned short*)((char*)d_ws + nc_bytes);
        unsigned short* wpn = (unsigned short*)((char*)d_ws + nc_bytes + wpe_bytes);
        float* gc = (float*)((char*)d_ws + nc_bytes + wpe_bytes + wpn_bytes);

        pack2_kernel<<<7, 256, 0, stream>>>(W, b, glob, wpe, wpn, gc);
        node3_kernel<<<(Nn + 63) / 64, 256, 0, stream>>>(nodes, wpn, NCb, Nn);

        int NT = (E + 63) / 64;                 // 64-edge block-tiles
        int grid = (NT < 2500) ? NT : 2500;
        int T = (NT + grid - 1) / grid;
        edge7_kernel<<<grid, 256, 0, stream>>>(edges, recv, send, wpe, NCb, gc, out, E, T);
    } else {
        unsigned short* wp = (unsigned short*)d_ws;
        float* gc = (float*)((char*)d_ws + NFRAG * 64 * 8 * 2);
        pack_kernel<<<7, 256, 0, stream>>>(W, b, glob, wp, gc);
        int nblk = (E + ITERS * 64 - 1) / (ITERS * 64);
        edge_kernel<<<nblk, 256, 0, stream>>>(edges, nodes, recv, send, wp, gc, out, E);
    }
}

// Round 8
// 196.316 us; speedup vs baseline: 1.9187x; 1.0523x over previous
//
#include <hip/hip_runtime.h>

typedef __attribute__((ext_vector_type(8))) short short8;
typedef __attribute__((ext_vector_type(4))) float floatx4;

#define D_NODE 64
#define D_OUT  64

static __device__ __forceinline__ unsigned short f2bf(float x) {
    unsigned int u = __float_as_uint(x);
    unsigned int r = u + 0x7FFFu + ((u >> 16) & 1u);
    return (unsigned short)(r >> 16);
}

static __device__ __forceinline__ short8 cvt2(floatx4 x, floatx4 y) {
    short8 a;
    a[0] = (short)f2bf(x[0]); a[1] = (short)f2bf(x[1]);
    a[2] = (short)f2bf(x[2]); a[3] = (short)f2bf(x[3]);
    a[4] = (short)f2bf(y[0]); a[5] = (short)f2bf(y[1]);
    a[6] = (short)f2bf(y[2]); a[7] = (short)f2bf(y[3]);
    return a;
}

static __device__ __forceinline__ short8 load_cvt(const float* __restrict__ p) {
    return cvt2(*(const floatx4*)p, *(const floatx4*)(p + 4));
}

static __device__ __forceinline__ floatx4 ntload4(const float* __restrict__ p) {
    return __builtin_nontemporal_load((const floatx4*)p);
}

// Permuted W packing (R3): lane owns 16 contiguous out cols.
__global__ void pack2_kernel(const float* __restrict__ W, const float* __restrict__ b,
                             const float* __restrict__ g,
                             unsigned short* __restrict__ wpe,
                             unsigned short* __restrict__ wpn,
                             float* __restrict__ gc) {
    int tid = blockIdx.x * 256 + threadIdx.x;
    if (tid < 512) {
        int lane = tid & 63;
        int ct = (tid >> 6) & 3;
        int kstep = tid >> 8;
        int kbase = kstep * 32 + (lane >> 4) * 8;
        int col = 4 * (lane & 15) + ct;
        short8 sv;
#pragma unroll
        for (int j = 0; j < 8; ++j)
            sv[j] = (short)f2bf(W[(size_t)(kbase + j) * D_OUT + col]);
        *(short8*)(wpe + (size_t)tid * 8) = sv;
    } else if (tid < 512 + 1024) {
        int t = tid - 512;
        int lane = t & 63;
        int ct = (t >> 6) & 7;
        int kstep = t >> 9;
        int kk = kstep * 32 + (lane >> 4) * 8;
        int seg = (ct < 4) ? 64 : 128;
        int col = 4 * (lane & 15) + (ct & 3);
        short8 sv;
#pragma unroll
        for (int j = 0; j < 8; ++j)
            sv[j] = (short)f2bf(W[(size_t)(seg + kk + j) * D_OUT + col]);
        *(short8*)(wpn + (size_t)t * 8) = sv;
    } else if (tid < 512 + 1024 + 64) {
        int col = tid - 1536;
        float acc = b[col];
#pragma unroll
        for (int k = 0; k < 32; ++k)
            acc += g[k] * W[(size_t)(192 + k) * D_OUT + col];
        gc[col] = acc;
    }
}

// NC (bf16): NC[i][0:64] = nodes[i]@W[64:128], NC[i][64:128] = nodes[i]@W[128:192]
__global__ __launch_bounds__(256) void node3_kernel(
    const float* __restrict__ nodes, const unsigned short* __restrict__ wpn,
    unsigned short* __restrict__ NCb, int Nn) {
    const int lane = threadIdx.x & 63;
    const int wave = threadIdx.x >> 6;
    const int g = lane >> 4;
    int nbase = blockIdx.x * 64 + wave * 16;
    if (nbase >= Nn) return;

    int na = nbase + (lane & 15);
    bool valid = na < Nn;
    if (!valid) na = Nn - 1;
    const float* pn = nodes + (size_t)na * D_NODE + g * 8;
    short8 N0 = load_cvt(pn);
    short8 N1 = load_cvt(pn + 32);

    floatx4 acc[8];
#pragma unroll
    for (int ct = 0; ct < 8; ++ct) {
        short8 B0 = *(const short8*)(wpn + ((size_t)ct * 64 + lane) * 8);
        short8 B1 = *(const short8*)(wpn + ((size_t)(8 + ct) * 64 + lane) * 8);
        acc[ct] = (floatx4){0.f, 0.f, 0.f, 0.f};
        acc[ct] = __builtin_amdgcn_mfma_f32_16x16x32_bf16(B0, N0, acc[ct], 0, 0, 0);
        acc[ct] = __builtin_amdgcn_mfma_f32_16x16x32_bf16(B1, N1, acc[ct], 0, 0, 0);
    }
    if (valid) {
        unsigned short* pr = NCb + (size_t)na * 128 + 16 * g;
#pragma unroll
        for (int j = 0; j < 4; ++j) {
            unsigned short rv[4], sv[4];
#pragma unroll
            for (int ct = 0; ct < 4; ++ct) { rv[ct] = f2bf(acc[ct][j]); sv[ct] = f2bf(acc[4 + ct][j]); }
            *(uint2*)(pr + 4 * j) = *(uint2*)rv;
            *(uint2*)(pr + 64 + 4 * j) = *(uint2*)sv;
        }
    }
}

struct EdgeRegs { floatx4 v0, v1, v2, v3; };
struct GathRegs { uint2 r0, r1, r2, r3, s0, s1, s2, s3; };
struct IdxRegs  { int r0, r1, r2, r3, s0, s1, s2, s3; };

// Per-wave LDS region: [16 rows][16 chunks of 16B], chunk slot = chunk ^ (row&7).
// Used for BOTH the input (edge) tile and, after the MFMA reads, the output
// transpose — same region, DS program order guarantees safety.
__global__ __launch_bounds__(256) void edge8_kernel(
    const float* __restrict__ edges,
    const int* __restrict__ recv, const int* __restrict__ send,
    const unsigned short* __restrict__ wpe, const unsigned short* __restrict__ NCb,
    const float* __restrict__ gc, float* __restrict__ out, int E, int T) {

    __shared__ char lds[4][2][4096];   // 2 regions per wave (double buffer)

    const int lane = threadIdx.x & 63;
    const int wave = threadIdx.x >> 6;
    const int g = lane >> 4;     // MFMA k-group
    const int e16 = lane & 15;   // MFMA edge-row within tile
    const int c = lane & 15;     // stream 16B chunk id (out cols [4c,4c+4))
    const int lr = lane >> 4;    // stream row-subindex
    const int stride = gridDim.x;
    const int t0 = blockIdx.x;

    short8 Bf[8];
#pragma unroll
    for (int fi = 0; fi < 8; ++fi)
        Bf[fi] = *(const short8*)(wpe + ((size_t)fi * 64 + lane) * 8);

    const floatx4 gc4 = *(const floatx4*)(gc + 4 * c);

#define TBASE(k) ((t0 + (k) * stride) * 64 + wave * 16)

    auto load_idx = [&](int b) {
        IdxRegs I;
        int q0 = b + 0 + lr;  q0 = (q0 < E) ? q0 : E - 1;
        int q1 = b + 4 + lr;  q1 = (q1 < E) ? q1 : E - 1;
        int q2 = b + 8 + lr;  q2 = (q2 < E) ? q2 : E - 1;
        int q3 = b + 12 + lr; q3 = (q3 < E) ? q3 : E - 1;
        I.r0 = recv[q0]; I.r1 = recv[q1]; I.r2 = recv[q2]; I.r3 = recv[q3];
        I.s0 = send[q0]; I.s1 = send[q1]; I.s2 = send[q2]; I.s3 = send[q3];
        return I;
    };
    // Stream-layout edge loads: instr i covers 4 rows x 256B = 16 FULL lines.
    // Lane slot ci = i*64+lane -> row ci>>4, LDS chunk ci&15 holds global
    // chunk (ci&15)^((ci>>4)&7)  (inverse-swizzled source, linear LDS write).
    auto load_edges = [&](int b) {
        EdgeRegs Er;
#pragma unroll
        for (int i = 0; i < 4; ++i) {
            int ci = i * 64 + lane;
            int row = b + (ci >> 4);
            row = (row < E) ? row : E - 1;
            int gch = (ci & 15) ^ ((ci >> 4) & 7);
            const float* p = edges + (size_t)row * D_NODE + gch * 4;
            floatx4 v = ntload4(p);
            if (i == 0) Er.v0 = v; else if (i == 1) Er.v1 = v;
            else if (i == 2) Er.v2 = v; else Er.v3 = v;
        }
        return Er;
    };
    auto stage_edges = [&](char* buf, const EdgeRegs& Er) {
        *(floatx4*)(buf + (0 * 64 + lane) * 16) = Er.v0;
        *(floatx4*)(buf + (1 * 64 + lane) * 16) = Er.v1;
        *(floatx4*)(buf + (2 * 64 + lane) * 16) = Er.v2;
        *(floatx4*)(buf + (3 * 64 + lane) * 16) = Er.v3;
    };
    auto load_gath = [&](const IdxRegs& I) {
        GathRegs G;
        G.r0 = *(const uint2*)(NCb + (size_t)I.r0 * 128 + 4 * c);
        G.r1 = *(const uint2*)(NCb + (size_t)I.r1 * 128 + 4 * c);
        G.r2 = *(const uint2*)(NCb + (size_t)I.r2 * 128 + 4 * c);
        G.r3 = *(const uint2*)(NCb + (size_t)I.r3 * 128 + 4 * c);
        G.s0 = *(const uint2*)(NCb + (size_t)I.s0 * 128 + 64 + 4 * c);
        G.s1 = *(const uint2*)(NCb + (size_t)I.s1 * 128 + 64 + 4 * c);
        G.s2 = *(const uint2*)(NCb + (size_t)I.s2 * 128 + 64 + 4 * c);
        G.s3 = *(const uint2*)(NCb + (size_t)I.s3 * 128 + 64 + 4 * c);
        return G;
    };
    auto addg = [&](floatx4 v, uint2 r, uint2 s) {
        v[0] += __uint_as_float(r.x << 16) + __uint_as_float(s.x << 16);
        v[1] += __uint_as_float(r.x & 0xFFFF0000u) + __uint_as_float(s.x & 0xFFFF0000u);
        v[2] += __uint_as_float(r.y << 16) + __uint_as_float(s.y << 16);
        v[3] += __uint_as_float(r.y & 0xFFFF0000u) + __uint_as_float(s.y & 0xFFFF0000u);
        return v;
    };

    auto compute_store = [&](char* buf, int b0, const GathRegs& G) {
        const int s = (e16 & 7);
        // MFMA-layout reads: lane needs chunks {2g,2g+1,8+2g,9+2g} of row e16
        floatx4 a0lo = *(const floatx4*)(buf + e16 * 256 + ((2 * g + 0) ^ s) * 16);
        floatx4 a0hi = *(const floatx4*)(buf + e16 * 256 + ((2 * g + 1) ^ s) * 16);
        floatx4 a1lo = *(const floatx4*)(buf + e16 * 256 + ((2 * g + 8) ^ s) * 16);
        floatx4 a1hi = *(const floatx4*)(buf + e16 * 256 + ((2 * g + 9) ^ s) * 16);
        short8 A0 = cvt2(a0lo, a0hi);
        short8 A1 = cvt2(a1lo, a1hi);

        floatx4 acc0 = {0,0,0,0}, acc1 = {0,0,0,0}, acc2 = {0,0,0,0}, acc3 = {0,0,0,0};
        acc0 = __builtin_amdgcn_mfma_f32_16x16x32_bf16(Bf[0], A0, acc0, 0, 0, 0);
        acc1 = __builtin_amdgcn_mfma_f32_16x16x32_bf16(Bf[1], A0, acc1, 0, 0, 0);
        acc2 = __builtin_amdgcn_mfma_f32_16x16x32_bf16(Bf[2], A0, acc2, 0, 0, 0);
        acc3 = __builtin_amdgcn_mfma_f32_16x16x32_bf16(Bf[3], A0, acc3, 0, 0, 0);
        acc0 = __builtin_amdgcn_mfma_f32_16x16x32_bf16(Bf[4], A1, acc0, 0, 0, 0);
        acc1 = __builtin_amdgcn_mfma_f32_16x16x32_bf16(Bf[5], A1, acc1, 0, 0, 0);
        acc2 = __builtin_amdgcn_mfma_f32_16x16x32_bf16(Bf[6], A1, acc2, 0, 0, 0);
        acc3 = __builtin_amdgcn_mfma_f32_16x16x32_bf16(Bf[7], A1, acc3, 0, 0, 0);

        // acc{ct}[j] = out chunk 4g+j (cols 16g+4j+ct) of row e16
#pragma unroll
        for (int j = 0; j < 4; ++j) {
            floatx4 v = (floatx4){acc0[j], acc1[j], acc2[j], acc3[j]};
            *(floatx4*)(buf + e16 * 256 + ((4 * g + j) ^ s) * 16) = v;
        }

        // stream out: step i = rows b0+4i..+3, nt full-line stores
#pragma unroll
        for (int i = 0; i < 4; ++i) {
            int r = 4 * i + lr;
            floatx4 v = *(const floatx4*)(buf + r * 256 + (c ^ (r & 7)) * 16);
            v += gc4;
            if (i == 0) v = addg(v, G.r0, G.s0);
            else if (i == 1) v = addg(v, G.r1, G.s1);
            else if (i == 2) v = addg(v, G.r2, G.s2);
            else v = addg(v, G.r3, G.s3);
            int row = b0 + r;
            if (row < E)
                __builtin_nontemporal_store(v, (floatx4*)(out + (size_t)row * D_OUT + 4 * c));
        }
    };

    // ---- prologue ----
    IdxRegs I0 = load_idx(TBASE(0));
    IdxRegs In = (T > 1) ? load_idx(TBASE(1)) : I0;
    {
        EdgeRegs E0 = load_edges(TBASE(0));
        stage_edges(&lds[wave][0][0], E0);
    }
    GathRegs Gcur = load_gath(I0);
    int cur = 0;

#pragma unroll 1
    for (int k = 0; k < T; ++k) {
        const bool more = (k + 1 < T);
        EdgeRegs Ern;
        GathRegs Gnext;
        if (more) {
            Ern = load_edges(TBASE(k + 1));   // async into regs, lands during compute
            Gnext = load_gath(In);
        }
        IdxRegs I2 = In;
        if (k + 2 < T) I2 = load_idx(TBASE(k + 2));

        compute_store(&lds[wave][cur][0], TBASE(k), Gcur);

        if (more) stage_edges(&lds[wave][cur ^ 1][0], Ern);

        Gcur = Gnext; In = I2; cur ^= 1;
    }
#undef TBASE
}

// ---------------- Fallback path (round-1 kernel) if ws too small ----------------

#define NKSTEP 6
#define NFRAG  (NKSTEP * 4)
#define ITERS 4

__global__ void pack_kernel(const float* __restrict__ W, const float* __restrict__ b,
                            const float* __restrict__ g,
                            unsigned short* __restrict__ wp, float* __restrict__ gc) {
    int tid = blockIdx.x * 256 + threadIdx.x;
    if (tid < NFRAG * 64) {
        int lane = tid & 63;
        int ct = (tid >> 6) & 3;
        int kstep = tid >> 8;
        int kbase = kstep * 32 + (lane >> 4) * 8;
        int col = ct * 16 + (lane & 15);
        short8 sv;
#pragma unroll
        for (int j = 0; j < 8; ++j)
            sv[j] = (short)f2bf(W[(size_t)(kbase + j) * D_OUT + col]);
        *(short8*)(wp + (size_t)tid * 8) = sv;
    } else if (tid < NFRAG * 64 + 64) {
        int col = tid - NFRAG * 64;
        float acc = b[col];
#pragma unroll
        for (int k = 0; k < 32; ++k)
            acc += g[k] * W[(size_t)(192 + k) * D_OUT + col];
        gc[col] = acc;
    }
}

__global__ __launch_bounds__(256) void edge_kernel(
    const float* __restrict__ edges, const float* __restrict__ nodes,
    const int* __restrict__ recv, const int* __restrict__ send,
    const unsigned short* __restrict__ wp, const float* __restrict__ gc,
    float* __restrict__ out, int E) {

    const int lane = threadIdx.x & 63;
    const int wave = threadIdx.x >> 6;

    short8 Bf[NFRAG];
#pragma unroll
    for (int fi = 0; fi < NFRAG; ++fi)
        Bf[fi] = *(const short8*)(wp + ((size_t)fi * 64 + lane) * 8);

    const int colbase = lane & 15;
    float gv[4];
#pragma unroll
    for (int ct = 0; ct < 4; ++ct) gv[ct] = gc[ct * 16 + colbase];

    const int koff = (lane >> 4) * 8;

    for (int it = 0; it < ITERS; ++it) {
        int ebase = (blockIdx.x * ITERS + it) * 64 + wave * 16;
        if (ebase >= E) break;

        int ea = ebase + (lane & 15);
        if (ea >= E) ea = E - 1;
        int ri = recv[ea];
        int si = send[ea];

        const float* pe = edges + (size_t)ea * D_NODE + koff;
        const float* pr = nodes + (size_t)ri * D_NODE + koff;
        const float* ps = nodes + (size_t)si * D_NODE + koff;

        short8 A[NKSTEP];
        A[0] = load_cvt(pe);
        A[1] = load_cvt(pe + 32);
        A[2] = load_cvt(pr);
        A[3] = load_cvt(pr + 32);
        A[4] = load_cvt(ps);
        A[5] = load_cvt(ps + 32);

        floatx4 acc[4];
#pragma unroll
        for (int ct = 0; ct < 4; ++ct)
            acc[ct] = (floatx4){gv[ct], gv[ct], gv[ct], gv[ct]};

#pragma unroll
        for (int ks = 0; ks < NKSTEP; ++ks) {
#pragma unroll
            for (int ct = 0; ct < 4; ++ct)
                acc[ct] = __builtin_amdgcn_mfma_f32_16x16x32_bf16(
                    A[ks], Bf[ks * 4 + ct], acc[ct], 0, 0, 0);
        }

        int crow = ebase + (lane >> 4) * 4;
#pragma unroll
        for (int ct = 0; ct < 4; ++ct) {
#pragma unroll
            for (int r4 = 0; r4 < 4; ++r4) {
                int row = crow + r4;
                if (row < E)
                    out[(size_t)row * D_OUT + ct * 16 + colbase] = acc[ct][r4];
            }
        }
    }
}

extern "C" void kernel_launch(void* const* d_in, const int* in_sizes, int n_in,
                              void* d_out, int out_size, void* d_ws, size_t ws_size,
                              hipStream_t stream) {
    const float* edges = (const float*)d_in[0];
    const float* nodes = (const float*)d_in[1];
    const float* glob  = (const float*)d_in[2];
    const int*   recv  = (const int*)d_in[3];
    const int*   send  = (const int*)d_in[4];
    const float* W     = (const float*)d_in[5];
    const float* b     = (const float*)d_in[6];
    float* out = (float*)d_out;

    int E  = in_sizes[0] / D_NODE;
    int Nn = in_sizes[1] / D_NODE;

    size_t nc_bytes  = (size_t)Nn * 128 * 2;   // bf16 NC
    size_t wpe_bytes = 512 * 8 * 2;
    size_t wpn_bytes = 1024 * 8 * 2;
    size_t need = nc_bytes + wpe_bytes + wpn_bytes + 256;

    if (ws_size >= need) {
        unsigned short* NCb = (unsigned short*)d_ws;
        unsigned short* wpe = (unsigned short*)((char*)d_ws + nc_bytes);
        unsigned short* wpn = (unsigned short*)((char*)d_ws + nc_bytes + wpe_bytes);
        float* gc = (float*)((char*)d_ws + nc_bytes + wpe_bytes + wpn_bytes);

        pack2_kernel<<<7, 256, 0, stream>>>(W, b, glob, wpe, wpn, gc);
        node3_kernel<<<(Nn + 63) / 64, 256, 0, stream>>>(nodes, wpn, NCb, Nn);

        int NT = (E + 63) / 64;
        int grid = (NT < 2500) ? NT : 2500;
        int T = (NT + grid - 1) / grid;
        edge8_kernel<<<grid, 256, 0, stream>>>(edges, recv, send, wpe, NCb, gc, out, E, T);
    } else {
        unsigned short* wp = (unsigned short*)d_ws;
        float* gc = (float*)((char*)d_ws + NFRAG * 64 * 8 * 2);
        pack_kernel<<<7, 256, 0, stream>>>(W, b, glob, wp, gc);
        int nblk = (E + ITERS * 64 - 1) / (ITERS * 64);
        edge_kernel<<<nblk, 256, 0, stream>>>(edges, nodes, recv, send, wp, gc, out, E);
    }
}

// Round 9
// 187.336 us; speedup vs baseline: 2.0107x; 1.0479x over previous
//
#include <hip/hip_runtime.h>

typedef __attribute__((ext_vector_type(8))) short short8;
typedef __attribute__((ext_vector_type(4))) float floatx4;

#define D_NODE 64
#define D_OUT  64

static __device__ __forceinline__ unsigned short f2bf(float x) {
    unsigned int u = __float_as_uint(x);
    unsigned int r = u + 0x7FFFu + ((u >> 16) & 1u);
    return (unsigned short)(r >> 16);
}

static __device__ __forceinline__ short8 cvt2(floatx4 x, floatx4 y) {
    short8 a;
    a[0] = (short)f2bf(x[0]); a[1] = (short)f2bf(x[1]);
    a[2] = (short)f2bf(x[2]); a[3] = (short)f2bf(x[3]);
    a[4] = (short)f2bf(y[0]); a[5] = (short)f2bf(y[1]);
    a[6] = (short)f2bf(y[2]); a[7] = (short)f2bf(y[3]);
    return a;
}

static __device__ __forceinline__ short8 load_cvt(const float* __restrict__ p) {
    return cvt2(*(const floatx4*)p, *(const floatx4*)(p + 4));
}

static __device__ __forceinline__ floatx4 ntload4(const float* __restrict__ p) {
    return __builtin_nontemporal_load((const floatx4*)p);
}

// Permuted W packing (R3): lane owns 16 contiguous out cols.
__global__ void pack2_kernel(const float* __restrict__ W, const float* __restrict__ b,
                             const float* __restrict__ g,
                             unsigned short* __restrict__ wpe,
                             unsigned short* __restrict__ wpn,
                             float* __restrict__ gc) {
    int tid = blockIdx.x * 256 + threadIdx.x;
    if (tid < 512) {
        int lane = tid & 63;
        int ct = (tid >> 6) & 3;
        int kstep = tid >> 8;
        int kbase = kstep * 32 + (lane >> 4) * 8;
        int col = 4 * (lane & 15) + ct;
        short8 sv;
#pragma unroll
        for (int j = 0; j < 8; ++j)
            sv[j] = (short)f2bf(W[(size_t)(kbase + j) * D_OUT + col]);
        *(short8*)(wpe + (size_t)tid * 8) = sv;
    } else if (tid < 512 + 1024) {
        int t = tid - 512;
        int lane = t & 63;
        int ct = (t >> 6) & 7;
        int kstep = t >> 9;
        int kk = kstep * 32 + (lane >> 4) * 8;
        int seg = (ct < 4) ? 64 : 128;
        int col = 4 * (lane & 15) + (ct & 3);
        short8 sv;
#pragma unroll
        for (int j = 0; j < 8; ++j)
            sv[j] = (short)f2bf(W[(size_t)(seg + kk + j) * D_OUT + col]);
        *(short8*)(wpn + (size_t)t * 8) = sv;
    } else if (tid < 512 + 1024 + 64) {
        int col = tid - 1536;
        float acc = b[col];
#pragma unroll
        for (int k = 0; k < 32; ++k)
            acc += g[k] * W[(size_t)(192 + k) * D_OUT + col];
        gc[col] = acc;
    }
}

// NC (bf16): NC[i][0:64] = nodes[i]@W[64:128], NC[i][64:128] = nodes[i]@W[128:192]
__global__ __launch_bounds__(256) void node3_kernel(
    const float* __restrict__ nodes, const unsigned short* __restrict__ wpn,
    unsigned short* __restrict__ NCb, int Nn) {
    const int lane = threadIdx.x & 63;
    const int wave = threadIdx.x >> 6;
    const int g = lane >> 4;
    int nbase = blockIdx.x * 64 + wave * 16;
    if (nbase >= Nn) return;

    int na = nbase + (lane & 15);
    bool valid = na < Nn;
    if (!valid) na = Nn - 1;
    const float* pn = nodes + (size_t)na * D_NODE + g * 8;
    short8 N0 = load_cvt(pn);
    short8 N1 = load_cvt(pn + 32);

    floatx4 acc[8];
#pragma unroll
    for (int ct = 0; ct < 8; ++ct) {
        short8 B0 = *(const short8*)(wpn + ((size_t)ct * 64 + lane) * 8);
        short8 B1 = *(const short8*)(wpn + ((size_t)(8 + ct) * 64 + lane) * 8);
        acc[ct] = (floatx4){0.f, 0.f, 0.f, 0.f};
        acc[ct] = __builtin_amdgcn_mfma_f32_16x16x32_bf16(B0, N0, acc[ct], 0, 0, 0);
        acc[ct] = __builtin_amdgcn_mfma_f32_16x16x32_bf16(B1, N1, acc[ct], 0, 0, 0);
    }
    if (valid) {
        unsigned short* pr = NCb + (size_t)na * 128 + 16 * g;
#pragma unroll
        for (int j = 0; j < 4; ++j) {
            unsigned short rv[4], sv[4];
#pragma unroll
            for (int ct = 0; ct < 4; ++ct) { rv[ct] = f2bf(acc[ct][j]); sv[ct] = f2bf(acc[4 + ct][j]); }
            *(uint2*)(pr + 4 * j) = *(uint2*)rv;
            *(uint2*)(pr + 64 + 4 * j) = *(uint2*)sv;
        }
    }
}

struct EdgeRegs { floatx4 v0, v1, v2, v3; };
struct GathRegs { uint2 r0, r1, r2, r3, s0, s1, s2, s3; };
struct IdxRegs  { int r0, r1, r2, r3, s0, s1, s2, s3; };

// edge9: R8 structure + 2-tile-deep data prefetch.
//   iter k issues edges/gathers for tile k+2 (2 compute phases in flight),
//   stages tile k+1's edges to LDS after compute k, idx prefetched 3 ahead.
__global__ __launch_bounds__(256) void edge9_kernel(
    const float* __restrict__ edges,
    const int* __restrict__ recv, const int* __restrict__ send,
    const unsigned short* __restrict__ wpe, const unsigned short* __restrict__ NCb,
    const float* __restrict__ gc, float* __restrict__ out, int E, int T) {

    __shared__ char lds[4][2][4096];   // 2 regions per wave (double buffer)

    const int lane = threadIdx.x & 63;
    const int wave = threadIdx.x >> 6;
    const int g = lane >> 4;     // MFMA k-group
    const int e16 = lane & 15;   // MFMA edge-row within tile
    const int c = lane & 15;     // stream 16B chunk id (out cols [4c,4c+4))
    const int lr = lane >> 4;    // stream row-subindex
    const int stride = gridDim.x;
    const int t0 = blockIdx.x;

    short8 Bf[8];
#pragma unroll
    for (int fi = 0; fi < 8; ++fi)
        Bf[fi] = *(const short8*)(wpe + ((size_t)fi * 64 + lane) * 8);

    const floatx4 gc4 = *(const floatx4*)(gc + 4 * c);

#define TBASE(k) ((t0 + (k) * stride) * 64 + wave * 16)

    auto load_idx = [&](int b) {
        IdxRegs I;
        int q0 = b + 0 + lr;  q0 = (q0 < E) ? q0 : E - 1;
        int q1 = b + 4 + lr;  q1 = (q1 < E) ? q1 : E - 1;
        int q2 = b + 8 + lr;  q2 = (q2 < E) ? q2 : E - 1;
        int q3 = b + 12 + lr; q3 = (q3 < E) ? q3 : E - 1;
        I.r0 = recv[q0]; I.r1 = recv[q1]; I.r2 = recv[q2]; I.r3 = recv[q3];
        I.s0 = send[q0]; I.s1 = send[q1]; I.s2 = send[q2]; I.s3 = send[q3];
        return I;
    };
    // Stream-layout edge loads: instr i covers 4 rows x 256B = 16 FULL lines.
    auto load_edges = [&](int b) {
        EdgeRegs Er;
#pragma unroll
        for (int i = 0; i < 4; ++i) {
            int ci = i * 64 + lane;
            int row = b + (ci >> 4);
            row = (row < E) ? row : E - 1;
            int gch = (ci & 15) ^ ((ci >> 4) & 7);
            const float* p = edges + (size_t)row * D_NODE + gch * 4;
            floatx4 v = ntload4(p);
            if (i == 0) Er.v0 = v; else if (i == 1) Er.v1 = v;
            else if (i == 2) Er.v2 = v; else Er.v3 = v;
        }
        return Er;
    };
    auto stage_edges = [&](char* buf, const EdgeRegs& Er) {
        *(floatx4*)(buf + (0 * 64 + lane) * 16) = Er.v0;
        *(floatx4*)(buf + (1 * 64 + lane) * 16) = Er.v1;
        *(floatx4*)(buf + (2 * 64 + lane) * 16) = Er.v2;
        *(floatx4*)(buf + (3 * 64 + lane) * 16) = Er.v3;
    };
    auto load_gath = [&](const IdxRegs& I) {
        GathRegs G;
        G.r0 = *(const uint2*)(NCb + (size_t)I.r0 * 128 + 4 * c);
        G.r1 = *(const uint2*)(NCb + (size_t)I.r1 * 128 + 4 * c);
        G.r2 = *(const uint2*)(NCb + (size_t)I.r2 * 128 + 4 * c);
        G.r3 = *(const uint2*)(NCb + (size_t)I.r3 * 128 + 4 * c);
        G.s0 = *(const uint2*)(NCb + (size_t)I.s0 * 128 + 64 + 4 * c);
        G.s1 = *(const uint2*)(NCb + (size_t)I.s1 * 128 + 64 + 4 * c);
        G.s2 = *(const uint2*)(NCb + (size_t)I.s2 * 128 + 64 + 4 * c);
        G.s3 = *(const uint2*)(NCb + (size_t)I.s3 * 128 + 64 + 4 * c);
        return G;
    };
    auto addg = [&](floatx4 v, uint2 r, uint2 s) {
        v[0] += __uint_as_float(r.x << 16) + __uint_as_float(s.x << 16);
        v[1] += __uint_as_float(r.x & 0xFFFF0000u) + __uint_as_float(s.x & 0xFFFF0000u);
        v[2] += __uint_as_float(r.y << 16) + __uint_as_float(s.y << 16);
        v[3] += __uint_as_float(r.y & 0xFFFF0000u) + __uint_as_float(s.y & 0xFFFF0000u);
        return v;
    };

    auto compute_store = [&](char* buf, int b0, const GathRegs& G) {
        const int s = (e16 & 7);
        floatx4 a0lo = *(const floatx4*)(buf + e16 * 256 + ((2 * g + 0) ^ s) * 16);
        floatx4 a0hi = *(const floatx4*)(buf + e16 * 256 + ((2 * g + 1) ^ s) * 16);
        floatx4 a1lo = *(const floatx4*)(buf + e16 * 256 + ((2 * g + 8) ^ s) * 16);
        floatx4 a1hi = *(const floatx4*)(buf + e16 * 256 + ((2 * g + 9) ^ s) * 16);
        short8 A0 = cvt2(a0lo, a0hi);
        short8 A1 = cvt2(a1lo, a1hi);

        floatx4 acc0 = {0,0,0,0}, acc1 = {0,0,0,0}, acc2 = {0,0,0,0}, acc3 = {0,0,0,0};
        acc0 = __builtin_amdgcn_mfma_f32_16x16x32_bf16(Bf[0], A0, acc0, 0, 0, 0);
        acc1 = __builtin_amdgcn_mfma_f32_16x16x32_bf16(Bf[1], A0, acc1, 0, 0, 0);
        acc2 = __builtin_amdgcn_mfma_f32_16x16x32_bf16(Bf[2], A0, acc2, 0, 0, 0);
        acc3 = __builtin_amdgcn_mfma_f32_16x16x32_bf16(Bf[3], A0, acc3, 0, 0, 0);
        acc0 = __builtin_amdgcn_mfma_f32_16x16x32_bf16(Bf[4], A1, acc0, 0, 0, 0);
        acc1 = __builtin_amdgcn_mfma_f32_16x16x32_bf16(Bf[5], A1, acc1, 0, 0, 0);
        acc2 = __builtin_amdgcn_mfma_f32_16x16x32_bf16(Bf[6], A1, acc2, 0, 0, 0);
        acc3 = __builtin_amdgcn_mfma_f32_16x16x32_bf16(Bf[7], A1, acc3, 0, 0, 0);

#pragma unroll
        for (int j = 0; j < 4; ++j) {
            floatx4 v = (floatx4){acc0[j], acc1[j], acc2[j], acc3[j]};
            *(floatx4*)(buf + e16 * 256 + ((4 * g + j) ^ s) * 16) = v;
        }

#pragma unroll
        for (int i = 0; i < 4; ++i) {
            int r = 4 * i + lr;
            floatx4 v = *(const floatx4*)(buf + r * 256 + (c ^ (r & 7)) * 16);
            v += gc4;
            if (i == 0) v = addg(v, G.r0, G.s0);
            else if (i == 1) v = addg(v, G.r1, G.s1);
            else if (i == 2) v = addg(v, G.r2, G.s2);
            else v = addg(v, G.r3, G.s3);
            int row = b0 + r;
            if (row < E)
                __builtin_nontemporal_store(v, (floatx4*)(out + (size_t)row * D_OUT + 4 * c));
        }
    };

    // ---- prologue: tiles 0,1 data in flight; idx up to tile 2 ----
    IdxRegs I0 = load_idx(TBASE(0));
    IdxRegs I1 = (T > 1) ? load_idx(TBASE(1)) : I0;
    IdxRegs In = (T > 2) ? load_idx(TBASE(2)) : I1;   // idx for tile k+2

    {
        EdgeRegs E0 = load_edges(TBASE(0));
        stage_edges(&lds[wave][0][0], E0);
    }
    GathRegs G0 = load_gath(I0);                      // for tile k
    EdgeRegs E1;                                      // edges for tile k+1 (regs)
    GathRegs G1;                                      // gathers for tile k+1
    if (T > 1) {
        E1 = load_edges(TBASE(1));
        G1 = load_gath(I1);
    }
    int cur = 0;

#pragma unroll 1
    for (int k = 0; k < T; ++k) {
        // issue tile k+2 data loads (arrive during compute of k and k+1)
        EdgeRegs E2 = E1;
        GathRegs G2 = G1;
        if (k + 2 < T) {
            E2 = load_edges(TBASE(k + 2));
            G2 = load_gath(In);
        }
        IdxRegs I3 = In;
        if (k + 3 < T) I3 = load_idx(TBASE(k + 3));

        compute_store(&lds[wave][cur][0], TBASE(k), G0);

        if (k + 1 < T) stage_edges(&lds[wave][cur ^ 1][0], E1);

        E1 = E2; G0 = G1; G1 = G2; In = I3; cur ^= 1;
    }
#undef TBASE
}

// ---------------- Fallback path (round-1 kernel) if ws too small ----------------

#define NKSTEP 6
#define NFRAG  (NKSTEP * 4)
#define ITERS 4

__global__ void pack_kernel(const float* __restrict__ W, const float* __restrict__ b,
                            const float* __restrict__ g,
                            unsigned short* __restrict__ wp, float* __restrict__ gc) {
    int tid = blockIdx.x * 256 + threadIdx.x;
    if (tid < NFRAG * 64) {
        int lane = tid & 63;
        int ct = (tid >> 6) & 3;
        int kstep = tid >> 8;
        int kbase = kstep * 32 + (lane >> 4) * 8;
        int col = ct * 16 + (lane & 15);
        short8 sv;
#pragma unroll
        for (int j = 0; j < 8; ++j)
            sv[j] = (short)f2bf(W[(size_t)(kbase + j) * D_OUT + col]);
        *(short8*)(wp + (size_t)tid * 8) = sv;
    } else if (tid < NFRAG * 64 + 64) {
        int col = tid - NFRAG * 64;
        float acc = b[col];
#pragma unroll
        for (int k = 0; k < 32; ++k)
            acc += g[k] * W[(size_t)(192 + k) * D_OUT + col];
        gc[col] = acc;
    }
}

__global__ __launch_bounds__(256) void edge_kernel(
    const float* __restrict__ edges, const float* __restrict__ nodes,
    const int* __restrict__ recv, const int* __restrict__ send,
    const unsigned short* __restrict__ wp, const float* __restrict__ gc,
    float* __restrict__ out, int E) {

    const int lane = threadIdx.x & 63;
    const int wave = threadIdx.x >> 6;

    short8 Bf[NFRAG];
#pragma unroll
    for (int fi = 0; fi < NFRAG; ++fi)
        Bf[fi] = *(const short8*)(wp + ((size_t)fi * 64 + lane) * 8);

    const int colbase = lane & 15;
    float gv[4];
#pragma unroll
    for (int ct = 0; ct < 4; ++ct) gv[ct] = gc[ct * 16 + colbase];

    const int koff = (lane >> 4) * 8;

    for (int it = 0; it < ITERS; ++it) {
        int ebase = (blockIdx.x * ITERS + it) * 64 + wave * 16;
        if (ebase >= E) break;

        int ea = ebase + (lane & 15);
        if (ea >= E) ea = E - 1;
        int ri = recv[ea];
        int si = send[ea];

        const float* pe = edges + (size_t)ea * D_NODE + koff;
        const float* pr = nodes + (size_t)ri * D_NODE + koff;
        const float* ps = nodes + (size_t)si * D_NODE + koff;

        short8 A[NKSTEP];
        A[0] = load_cvt(pe);
        A[1] = load_cvt(pe + 32);
        A[2] = load_cvt(pr);
        A[3] = load_cvt(pr + 32);
        A[4] = load_cvt(ps);
        A[5] = load_cvt(ps + 32);

        floatx4 acc[4];
#pragma unroll
        for (int ct = 0; ct < 4; ++ct)
            acc[ct] = (floatx4){gv[ct], gv[ct], gv[ct], gv[ct]};

#pragma unroll
        for (int ks = 0; ks < NKSTEP; ++ks) {
#pragma unroll
            for (int ct = 0; ct < 4; ++ct)
                acc[ct] = __builtin_amdgcn_mfma_f32_16x16x32_bf16(
                    A[ks], Bf[ks * 4 + ct], acc[ct], 0, 0, 0);
        }

        int crow = ebase + (lane >> 4) * 4;
#pragma unroll
        for (int ct = 0; ct < 4; ++ct) {
#pragma unroll
            for (int r4 = 0; r4 < 4; ++r4) {
                int row = crow + r4;
                if (row < E)
                    out[(size_t)row * D_OUT + ct * 16 + colbase] = acc[ct][r4];
            }
        }
    }
}

extern "C" void kernel_launch(void* const* d_in, const int* in_sizes, int n_in,
                              void* d_out, int out_size, void* d_ws, size_t ws_size,
                              hipStream_t stream) {
    const float* edges = (const float*)d_in[0];
    const float* nodes = (const float*)d_in[1];
    const float* glob  = (const float*)d_in[2];
    const int*   recv  = (const int*)d_in[3];
    const int*   send  = (const int*)d_in[4];
    const float* W     = (const float*)d_in[5];
    const float* b     = (const float*)d_in[6];
    float* out = (float*)d_out;

    int E  = in_sizes[0] / D_NODE;
    int Nn = in_sizes[1] / D_NODE;

    size_t nc_bytes  = (size_t)Nn * 128 * 2;   // bf16 NC
    size_t wpe_bytes = 512 * 8 * 2;
    size_t wpn_bytes = 1024 * 8 * 2;
    size_t need = nc_bytes + wpe_bytes + wpn_bytes + 256;

    if (ws_size >= need) {
        unsigned short* NCb = (unsigned short*)d_ws;
        unsigned short* wpe = (unsigned short*)((char*)d_ws + nc_bytes);
        unsigned short* wpn = (unsigned short*)((char*)d_ws + nc_bytes + wpe_bytes);
        float* gc = (float*)((char*)d_ws + nc_bytes + wpe_bytes + wpn_bytes);

        pack2_kernel<<<7, 256, 0, stream>>>(W, b, glob, wpe, wpn, gc);
        node3_kernel<<<(Nn + 63) / 64, 256, 0, stream>>>(nodes, wpn, NCb, Nn);

        int NT = (E + 63) / 64;
        int grid = (NT < 2500) ? NT : 2500;
        int T = (NT + grid - 1) / grid;
        edge9_kernel<<<grid, 256, 0, stream>>>(edges, recv, send, wpe, NCb, gc, out, E, T);
    } else {
        unsigned short* wp = (unsigned short*)d_ws;
        float* gc = (float*)((char*)d_ws + NFRAG * 64 * 8 * 2);
        pack_kernel<<<7, 256, 0, stream>>>(W, b, glob, wp, gc);
        int nblk = (E + ITERS * 64 - 1) / (ITERS * 64);
        edge_kernel<<<nblk, 256, 0, stream>>>(edges, nodes, recv, send, wp, gc, out, E);
    }
}